// Round 13
// baseline (326.584 us; speedup 1.0000x reference)
//
#include <hip/hip_runtime.h>
#include <hip/hip_bf16.h>

typedef __hip_bfloat16 bf16;
typedef unsigned short ushort;
typedef __attribute__((ext_vector_type(8))) short short8;  // 8 bf16 (4 VGPRs)
typedef __attribute__((ext_vector_type(4))) float f32x4;   // 4 fp32 acc

__device__ __forceinline__ float b2f(bf16 h) { return __bfloat162float(h); }
__device__ __forceinline__ bf16 f2b(float f) { return __float2bfloat16(f); }
__device__ __forceinline__ ushort f2bu(float f) {
    bf16 t = __float2bfloat16(f);
    ushort u;
    __builtin_memcpy(&u, &t, 2);
    return u;
}
__device__ __forceinline__ float bits2f(unsigned int u16) {
    unsigned int v = u16 << 16;
    float f;
    __builtin_memcpy(&f, &v, 4);
    return f;
}

// ---- async global->LDS (16B per lane; LDS dest is wave-uniform base) ------
__device__ __forceinline__ void gload16(const void* g, void* l) {
    __builtin_amdgcn_global_load_lds(
        (const __attribute__((address_space(1))) void*)g,
        (__attribute__((address_space(3))) void*)l, 16, 0, 0);
}

// ---- runtime dtype probe (proven) -----------------------------------------
__global__ void detect_dtype_kernel(const unsigned short* __restrict__ x,
                                    int* __restrict__ flag) {
    __shared__ int cnt;
    if (threadIdx.x == 0) cnt = 0;
    __syncthreads();
    int local = 0;
    for (int i = threadIdx.x; i < 2048; i += 256) {
        float v = bits2f((unsigned int)x[i]);
        if (!(fabsf(v) < 1e4f)) local++;  // also true for NaN/Inf
    }
    atomicAdd(&cnt, local);
    __syncthreads();
    if (threadIdx.x == 0) flag[0] = (cnt >= 8) ? 1 : 0;
}

// ---- 8-elem loader for either dtype (runtime flag) ------------------------
__device__ __forceinline__ void load8f_rt(const void* p, int isf, float* f) {
    if (isf) {
        const float* q = (const float*)p;
        float4 a = *(const float4*)q;
        float4 b = *(const float4*)(q + 4);
        f[0] = a.x; f[1] = a.y; f[2] = a.z; f[3] = a.w;
        f[4] = b.x; f[5] = b.y; f[6] = b.z; f[7] = b.w;
    } else {
        uint4 u = *(const uint4*)p;
        f[0] = bits2f(u.x & 0xffffu); f[1] = bits2f(u.x >> 16);
        f[2] = bits2f(u.y & 0xffffu); f[3] = bits2f(u.y >> 16);
        f[4] = bits2f(u.z & 0xffffu); f[5] = bits2f(u.z >> 16);
        f[6] = bits2f(u.w & 0xffffu); f[7] = bits2f(u.w >> 16);
    }
}
__device__ __forceinline__ float loadf_rt(const void* p, int isf, size_t i) {
    return isf ? ((const float*)p)[i] : bits2f(((const ushort*)p)[i]);
}

// ---- one-time conversion (single kernel, runtime dtype) -------------------
// wall layout (ushort): wq@0 wk@589824 wv@1179648 wo@1769472 w1@2359296 w2@4718592
// vall layout (float):  bq@0 bk@768 bv@1536 bo@2304 b1@3072 b2@6144
//                       g1@6912 be1@7680 g2@8448 be2@9216   (total 9984)
__global__ __launch_bounds__(256) void conv_all_k(
    const int* __restrict__ dflag,
    const void* __restrict__ x,
    const void* __restrict__ wq, const void* __restrict__ wk,
    const void* __restrict__ wv, const void* __restrict__ wo,
    const void* __restrict__ w1, const void* __restrict__ w2,
    const void* __restrict__ bq, const void* __restrict__ bk,
    const void* __restrict__ bv, const void* __restrict__ bo,
    const void* __restrict__ b1, const void* __restrict__ b2,
    const void* __restrict__ g1, const void* __restrict__ be1,
    const void* __restrict__ g2, const void* __restrict__ be2,
    ushort* __restrict__ xb, ushort* __restrict__ wall,
    float* __restrict__ vall)
{
    const int isf = dflag[0];
    const int esz = isf ? 4 : 2;
    const int gt = blockIdx.x * 256 + threadIdx.x;
    const int stride = gridDim.x * 256;

    // x -> bf16
    for (int v = gt; v < 393216; v += stride) {  // 3,145,728 / 8
        float f[8];
        load8f_rt((const char*)x + (size_t)v * 8 * esz, isf, f);
        unsigned int wd[4];
        #pragma unroll
        for (int i = 0; i < 4; ++i)
            wd[i] = (unsigned int)f2bu(f[2 * i]) | ((unsigned int)f2bu(f[2 * i + 1]) << 16);
        *(uint4*)(xb + (size_t)v * 8) = make_uint4(wd[0], wd[1], wd[2], wd[3]);
    }
    // weights -> bf16
    for (int v = gt; v < 884736; v += stride) {  // 7,077,888 / 8
        const void* src; int loc;
        if (v < 73728)        { src = wq; loc = v; }
        else if (v < 147456)  { src = wk; loc = v - 73728; }
        else if (v < 221184)  { src = wv; loc = v - 147456; }
        else if (v < 294912)  { src = wo; loc = v - 221184; }
        else if (v < 589824)  { src = w1; loc = v - 294912; }
        else                  { src = w2; loc = v - 589824; }
        float f[8];
        load8f_rt((const char*)src + (size_t)loc * 8 * esz, isf, f);
        unsigned int wd[4];
        #pragma unroll
        for (int i = 0; i < 4; ++i)
            wd[i] = (unsigned int)f2bu(f[2 * i]) | ((unsigned int)f2bu(f[2 * i + 1]) << 16);
        *(uint4*)(wall + (size_t)v * 8) = make_uint4(wd[0], wd[1], wd[2], wd[3]);
    }
    // vectors -> f32
    for (int i = gt; i < 9984; i += stride) {
        const void* s; int l;
        if (i < 768)       { s = bq;  l = i; }
        else if (i < 1536) { s = bk;  l = i - 768; }
        else if (i < 2304) { s = bv;  l = i - 1536; }
        else if (i < 3072) { s = bo;  l = i - 2304; }
        else if (i < 6144) { s = b1;  l = i - 3072; }
        else if (i < 6912) { s = b2;  l = i - 6144; }
        else if (i < 7680) { s = g1;  l = i - 6912; }
        else if (i < 8448) { s = be1; l = i - 7680; }
        else if (i < 9216) { s = g2;  l = i - 8448; }
        else               { s = be2; l = i - 9216; }
        vall[i] = loadf_rt(s, isf, l);
    }
}

// ========== bf16 MFMA GEMM, BK=64, XOR-swizzled LDS, 2-phase dbuf ==========
// (round-5 verified inner structure; K-range [kstart, kstart+klen) for
// split-K; nullable bias.)
// Frag layouts (m89-verified): A-frag m=lane&15, k=quad*8+j;
// B-frag n=lane&15, k=quad*8+j; C/D col=lane&15, row=quad*4+reg.
template <int BM>
__device__ __forceinline__ void gemm_bf16_body(
    const ushort* __restrict__ A, const ushort* __restrict__ Bw,
    const float* __restrict__ bias, ushort* __restrict__ Cb,
    float* __restrict__ Cf, int N, int K, int kstart, int klen,
    int bm, int bn, int relu)
{
    __shared__ __align__(16) ushort As[2][BM][64];   // [buf][m][k], 128B rows
    __shared__ __align__(16) ushort Bs[2][128][64];  // [buf][n][k]
    const int tid = threadIdx.x;
    const int w = tid >> 6, lane = tid & 63;
    const int quad = lane >> 4, l15 = lane & 15;
    constexpr int FM = BM / 32;                    // frags per wave in M
    const int wr = (w >> 1) * (BM / 2), wc = (w & 1) * 64;

    constexpr int CA = (BM * 128) / 4096;          // 4KB rounds for A tile
    constexpr int CB = 4;                          // 128*128B/4KB
    size_t aoff[CA]; int albase[CA];
    #pragma unroll
    for (int c = 0; c < CA; ++c) {
        int byte = c * 4096 + tid * 16;
        int row = byte >> 7, colb = byte & 127;
        int csrc = colb ^ ((row & 7) << 4);        // inverse swizzle on SOURCE
        aoff[c] = (size_t)(bm + row) * K + (csrc >> 1);
        albase[c] = c * 4096 + w * 1024;           // wave-uniform LDS base
    }
    size_t boff[CB]; int blbase[CB];
    #pragma unroll
    for (int c = 0; c < CB; ++c) {
        int byte = c * 4096 + tid * 16;
        int row = byte >> 7, colb = byte & 127;
        int csrc = colb ^ ((row & 7) << 4);
        boff[c] = (size_t)(bn + row) * K + (csrc >> 1);
        blbase[c] = c * 4096 + w * 1024;
    }

    f32x4 acc[FM][4];
    #pragma unroll
    for (int i = 0; i < FM; ++i)
        #pragma unroll
        for (int j = 0; j < 4; ++j) acc[i][j] = (f32x4){0.f, 0.f, 0.f, 0.f};

    constexpr int ASZ = BM * 128;      // bytes per A buffer
    constexpr int BSZ = 128 * 128;     // bytes per B buffer

#define STAGE(buf, k0)                                                        \
    {                                                                         \
        char* ab = (char*)As + (buf) * ASZ;                                   \
        char* bb = (char*)Bs + (buf) * BSZ;                                   \
        _Pragma("unroll")                                                     \
        for (int c = 0; c < CA; ++c)                                          \
            gload16(A + aoff[c] + (k0), ab + albase[c]);                      \
        _Pragma("unroll")                                                     \
        for (int c = 0; c < CB; ++c)                                          \
            gload16(Bw + boff[c] + (k0), bb + blbase[c]);                     \
    }

    const int NT = klen >> 6;
    STAGE(0, kstart);
    int cur = 0;
    for (int t = 0; t < NT; ++t) {
        __syncthreads();                 // buf[cur] visible (vmcnt drained)
        if (t + 1 < NT) STAGE(cur ^ 1, kstart + (t + 1) * 64);

        const ushort (*Asb)[64] = As[cur];
        const ushort (*Bsb)[64] = Bs[cur];
        short8 af[FM][2], bfr[4][2];
        #pragma unroll
        for (int i = 0; i < FM; ++i) {
            int r = wr + i * 16 + l15;
            int sw = (r & 7) << 3;                 // XOR key in ushort units
            af[i][0] = *(const short8*)&Asb[r][(quad * 8) ^ sw];
            af[i][1] = *(const short8*)&Asb[r][(32 + quad * 8) ^ sw];
        }
        #pragma unroll
        for (int j = 0; j < 4; ++j) {
            int r = wc + j * 16 + l15;
            int sw = (r & 7) << 3;
            bfr[j][0] = *(const short8*)&Bsb[r][(quad * 8) ^ sw];
            bfr[j][1] = *(const short8*)&Bsb[r][(32 + quad * 8) ^ sw];
        }
        #pragma unroll
        for (int h = 0; h < 2; ++h)
            #pragma unroll
            for (int i = 0; i < FM; ++i)
                #pragma unroll
                for (int j = 0; j < 4; ++j)
                    acc[i][j] = __builtin_amdgcn_mfma_f32_16x16x32_bf16(
                        af[i][h], bfr[j][h], acc[i][j], 0, 0, 0);
        cur ^= 1;
    }
#undef STAGE

    #pragma unroll
    for (int j = 0; j < 4; ++j) {
        int col = bn + wc + j * 16 + l15;
        float bv = bias ? bias[col] : 0.f;
        #pragma unroll
        for (int i = 0; i < FM; ++i) {
            int row0 = bm + wr + i * 16 + quad * 4;
            #pragma unroll
            for (int r = 0; r < 4; ++r) {
                float vv = acc[i][j][r] + bv;
                if (relu) vv = fmaxf(vv, 0.f);
                size_t idx = (size_t)(row0 + r) * N + col;
                if (Cb) Cb[idx] = f2bu(vv);
                if (Cf) Cf[idx] = vv;
            }
        }
    }
}

// XCD-aware bijective block swizzle (grids here are all %8 == 0)
__device__ __forceinline__ int xcd_swz(int bid, int nwg) {
    int cpx = nwg >> 3;
    return (bid & 7) * cpx + (bid >> 3);
}

template <int BM>
__global__ __launch_bounds__(256) void gemm_b(
    const ushort* __restrict__ A, const ushort* __restrict__ Bw,
    const float* __restrict__ bias, ushort* __restrict__ Cb,
    float* __restrict__ Cf, int N, int K, int relu)
{
    int nwg = gridDim.x * gridDim.y;
    int bid = xcd_swz(blockIdx.y * gridDim.x + blockIdx.x, nwg);
    int bx = bid % gridDim.x, by = bid / gridDim.x;
    gemm_bf16_body<BM>(A, Bw, bias, Cb, Cf, N, K, 0, K, by * BM, bx * 128, relu);
}

// split-K x2 GEMM: grid (nx, ny, 2); part z writes f32 partial Cf + z*nxd;
// bias added in part 0 only. LN kernels downstream sum the two partials.
template <int BM>
__global__ __launch_bounds__(256) void gemm_ksplit(
    const ushort* __restrict__ A, const ushort* __restrict__ Bw,
    const float* __restrict__ bias, float* __restrict__ Cf, int N, int K)
{
    const int part = blockIdx.z;
    int nwg = gridDim.x * gridDim.y;
    int bid = xcd_swz(blockIdx.y * gridDim.x + blockIdx.x, nwg);
    int bx = bid % gridDim.x, by = bid / gridDim.x;
    const int kh = K >> 1;
    gemm_bf16_body<BM>(A, Bw, part ? nullptr : bias, nullptr,
                       Cf + (size_t)part * 3145728, N, K,
                       part * kh, kh, by * BM, bx * 128, 0);
}

// Fused QKV: grid.x = 18 (3 mats x 6 n-tiles), grid.y = 32 (m-tiles)
__global__ __launch_bounds__(256) void gemm_qkv_b(
    const ushort* __restrict__ x, const ushort* __restrict__ wall,
    const float* __restrict__ vall,
    ushort* __restrict__ qb, ushort* __restrict__ kb, ushort* __restrict__ vb)
{
    int bid = xcd_swz(blockIdx.y * 18 + blockIdx.x, 576);
    int bx = bid % 18, by = bid / 18;
    const int mat = bx / 6;
    const int bn = (bx % 6) * 128;
    const ushort* W = wall + (size_t)mat * 589824;
    const float* Bi = vall + mat * 768;
    ushort* O = (mat == 0) ? qb : (mat == 1) ? kb : vb;
    gemm_bf16_body<128>(x, W, Bi, O, nullptr, 768, 768, 0, 768, by * 128, bn, 0);
}

// ============== bf16 MFMA flash attention, split-K x2, 4-WAVE ==============
// Round-13 change: QBLK 128->64, block 512->256 threads. Per-block LDS
// ~31KB -> 5 RESIDENT BLOCKS/CU (was 3 at 40KB) -> 5 independent
// barrier-groups rotating per CU. Evidence: all 3-blocks/CU variants
// measured ~72us, all 2-blocks/CU variants 76-80us -> resident-block
// independence is the controlling variable for this latency-bound kernel.
// Compute core = round-9/10 verified (exp2 softmax, group-max, defer-max
// THR=11, ones-MFMA l, XOR-swizzled Ps, T14 reg prefetch, T1 XCD swizzle).
// Staging indices = round-1/2 verified 256-thread pattern.
__global__ __launch_bounds__(256) void attn_mfma_b(
    const ushort* __restrict__ q, const ushort* __restrict__ k,
    const ushort* __restrict__ v, const int* __restrict__ mask,
    float* __restrict__ opart, float* __restrict__ mlbuf)
{
    const int S = 2048, D = 768;
    const size_t NXD = 3145728;
    const float SC2 = 0.125f * 1.44269504088896f;   // score scale in log2 units
    __shared__ __align__(16) ushort Ks[64][72];     // [key][dim]
    __shared__ __align__(16) ushort Vt[64][72];     // [dim][key]
    __shared__ __align__(16) ushort Ps[4][16][72];  // per-wave P, XOR-swizzled
    __shared__ float mkAll[1024];                   // additive mask bias (part)

    const int tid = threadIdx.x;
    const int w = tid >> 6, lane = tid & 63;        // w in 0..3
    const int quad = lane >> 4, l15 = lane & 15;

    // T1: XCD-chunked swizzle (bijective, 1536 % 8 == 0)
    const int bx = xcd_swz(blockIdx.x, 1536);
    const int part = bx / 768;
    const int rest = bx - part * 768;
    const int q0 = (rest & 31) * 64;                // 32 q-tiles of 64 rows
    const int h = (rest >> 5) % 12;
    const int b = rest / 384;
    const int kbase = part * 1024;

    // hoist the part's 1024 mask flags once
    #pragma unroll
    for (int i = 0; i < 4; ++i) {
        int idx = tid + i * 256;
        mkAll[idx] = mask[b * S + kbase + idx] ? -30000.f : 0.f;
    }

    const size_t qrow = (size_t)(b * S + q0 + w * 16 + l15) * D + h * 64;
    const short8 aQ0 = *(const short8*)&q[qrow + quad * 8];
    const short8 aQ1 = *(const short8*)&q[qrow + 32 + quad * 8];

    short8 ones;
    #pragma unroll
    for (int j = 0; j < 8; ++j) ones[j] = (short)0x3F80;  // bf16 1.0

    f32x4 o[4], lacc;
    #pragma unroll
    for (int i = 0; i < 4; ++i) o[i] = (f32x4){0.f, 0.f, 0.f, 0.f};
    lacc = (f32x4){0.f, 0.f, 0.f, 0.f};
    float m_run = -3.0e38f;

    const int sr = tid >> 2;          // K staging: key row 0..63
    const int sc0 = (tid & 3) * 16;   // K staging: dim base (ushorts)

    const ushort* kp = k + (size_t)(b * S + kbase + sr) * D + h * 64 + sc0;
    const ushort* vp = v + (size_t)(b * S + kbase + lane) * D + h * 64 + w * 16;
    uint4 ka0 = *(const uint4*)kp;
    uint4 ka1 = *(const uint4*)(kp + 8);
    uint4 va0 = *(const uint4*)vp;
    uint4 va1 = *(const uint4*)(vp + 8);

    for (int kt = 0; kt < 16; ++kt) {
        __syncthreads();  // previous tile's consumers done
        *(uint4*)&Ks[sr][sc0] = ka0;
        *(uint4*)&Ks[sr][sc0 + 8] = ka1;
        {   // conflict-free transpose: wave w owns dims [w*16, w*16+16)
            alignas(16) ushort tmp[16];
            *(uint4*)tmp = va0;
            *(uint4*)(tmp + 8) = va1;
            #pragma unroll
            for (int i = 0; i < 16; ++i) Vt[w * 16 + i][lane] = tmp[i];
        }
        __syncthreads();  // tile visible

        // ---- prefetch next tile (flies under compute) ----
        if (kt + 1 < 16) {
            kp += 64 * D;
            vp += 64 * D;
            ka0 = *(const uint4*)kp;
            ka1 = *(const uint4*)(kp + 8);
            va0 = *(const uint4*)vp;
            va1 = *(const uint4*)(vp + 8);
        }

        // ---- QK^T (log2 domain, additive mask) ----
        const float* mk = &mkAll[kt * 64];
        float scv[4][4];
        float vm = -3.0e38f;
        __builtin_amdgcn_s_setprio(1);
        #pragma unroll
        for (int s = 0; s < 4; ++s) {
            short8 bk0 = *(const short8*)&Ks[s * 16 + l15][quad * 8];
            short8 bk1 = *(const short8*)&Ks[s * 16 + l15][32 + quad * 8];
            f32x4 c = (f32x4){0.f, 0.f, 0.f, 0.f};
            c = __builtin_amdgcn_mfma_f32_16x16x32_bf16(aQ0, bk0, c, 0, 0, 0);
            c = __builtin_amdgcn_mfma_f32_16x16x32_bf16(aQ1, bk1, c, 0, 0, 0);
            float mb = mk[s * 16 + l15];
            #pragma unroll
            for (int r = 0; r < 4; ++r) {
                float val = __builtin_fmaf(c[r], SC2, mb);
                scv[s][r] = val;
                vm = fmaxf(vm, val);
            }
        }
        __builtin_amdgcn_s_setprio(0);
        // group max over keys (16 l15-lanes); shared by this quad's 4 q-rows
        vm = fmaxf(vm, __shfl_xor(vm, 1, 16));
        vm = fmaxf(vm, __shfl_xor(vm, 2, 16));
        vm = fmaxf(vm, __shfl_xor(vm, 4, 16));
        vm = fmaxf(vm, __shfl_xor(vm, 8, 16));

        // defer-max: rescale only when tile max grows past threshold
        if (__any(vm > m_run + 11.0f)) {
            float mn = fmaxf(m_run, vm);
            float alpha = exp2f(m_run - mn);
            #pragma unroll
            for (int s = 0; s < 4; ++s) o[s] *= alpha;
            lacc *= alpha;
            m_run = mn;
        }

        // P = exp2(scv - m_run) -> bf16, XOR-swizzled per-wave store
        #pragma unroll
        for (int r = 0; r < 4; ++r)
            #pragma unroll
            for (int s = 0; s < 4; ++s)
                Ps[w][quad * 4 + r][(s * 16 + l15) ^ (quad << 4)] =
                    f2bu(exp2f(scv[s][r] - m_run));
        asm volatile("s_waitcnt lgkmcnt(0)" ::: "memory");

        // ---- PV + l (ones column) ----
        {
            const int pswz = (l15 >> 2) << 4;
            short8 aP0 = *(const short8*)&Ps[w][l15][(quad * 8) ^ pswz];
            short8 aP1 = *(const short8*)&Ps[w][l15][(32 + quad * 8) ^ pswz];
            __builtin_amdgcn_s_setprio(1);
            lacc = __builtin_amdgcn_mfma_f32_16x16x32_bf16(aP0, ones, lacc, 0, 0, 0);
            lacc = __builtin_amdgcn_mfma_f32_16x16x32_bf16(aP1, ones, lacc, 0, 0, 0);
            #pragma unroll
            for (int s = 0; s < 4; ++s) {
                short8 bv0 = *(const short8*)&Vt[s * 16 + l15][quad * 8];
                short8 bv1 = *(const short8*)&Vt[s * 16 + l15][32 + quad * 8];
                o[s] = __builtin_amdgcn_mfma_f32_16x16x32_bf16(aP0, bv0, o[s], 0, 0, 0);
                o[s] = __builtin_amdgcn_mfma_f32_16x16x32_bf16(aP1, bv1, o[s], 0, 0, 0);
            }
            __builtin_amdgcn_s_setprio(0);
        }
    }

    // ---- epilogue: unnormalized f32 partial + (m,l) in log2 domain ----
    const size_t obase = (size_t)part * NXD +
                         (size_t)(b * S + q0 + w * 16) * D + h * 64;
    #pragma unroll
    for (int r = 0; r < 4; ++r)
        #pragma unroll
        for (int s = 0; s < 4; ++s)
            opart[obase + (size_t)(quad * 4 + r) * D + s * 16 + l15] = o[s][r];
    if (l15 == 0) {
        #pragma unroll
        for (int r = 0; r < 4; ++r) {
            int row = b * S + q0 + w * 16 + quad * 4 + r;
            size_t mi = (((size_t)part * 4096 + row) * 12 + h) * 2;
            mlbuf[mi] = m_run;
            mlbuf[mi + 1] = lacc[r];
        }
    }
}

// ---- combine 2 split-K partials -> bf16 ctx (log2-domain m,l) -------------
__global__ __launch_bounds__(256) void attn_combine(
    const float* __restrict__ opart, const float* __restrict__ mlbuf,
    ushort* __restrict__ ctx)
{
    const size_t NXD = 3145728;
    const int row = blockIdx.x;
    const int tid = threadIdx.x;
    #pragma unroll
    for (int i = 0; i < 3; ++i) {
        int d = tid + i * 256;
        int h = d >> 6;
        size_t m0i = ((size_t)row * 12 + h) * 2;
        size_t m1i = (((size_t)4096 + row) * 12 + h) * 2;
        float m0 = mlbuf[m0i], l0 = mlbuf[m0i + 1];
        float m1 = mlbuf[m1i], l1 = mlbuf[m1i + 1];
        float m = fmaxf(m0, m1);
        float e0 = exp2f(m0 - m), e1 = exp2f(m1 - m);
        float inv = 1.f / (l0 * e0 + l1 * e1);
        size_t idx = (size_t)row * 768 + d;
        float val = (opart[idx] * e0 + opart[NXD + idx] * e1) * inv;
        ctx[idx] = f2bu(val);
    }
}

// ---- LN1: out = LN(x + (r0+r1)); runtime x dtype; bf16 + f32 out ----------
__global__ __launch_bounds__(256) void ln1_kernel(
    const int* __restrict__ dflag,
    const void* __restrict__ xa, const float* __restrict__ r0,
    const float* __restrict__ r1,
    const float* __restrict__ gamma, const float* __restrict__ beta,
    ushort* __restrict__ outb, float* __restrict__ outf)
{
    const int isf = dflag[0];
    const int row = blockIdx.x;
    const int tid = threadIdx.x;
    __shared__ float red[4];
    const size_t base = (size_t)row * 768;

    float x[3];
    #pragma unroll
    for (int i = 0; i < 3; ++i) {
        int d = tid + i * 256;
        x[i] = loadf_rt(xa, isf, base + d) + r0[base + d] + r1[base + d];
    }

    float s = x[0] + x[1] + x[2];
    #pragma unroll
    for (int off = 32; off > 0; off >>= 1) s += __shfl_down(s, off, 64);
    if ((tid & 63) == 0) red[tid >> 6] = s;
    __syncthreads();
    float mean = (red[0] + red[1] + red[2] + red[3]) * (1.f / 768.f);
    __syncthreads();

    float vsum = 0.f;
    #pragma unroll
    for (int i = 0; i < 3; ++i) {
        float dd = x[i] - mean;
        vsum += dd * dd;
    }
    #pragma unroll
    for (int off = 32; off > 0; off >>= 1) vsum += __shfl_down(vsum, off, 64);
    if ((tid & 63) == 0) red[tid >> 6] = vsum;
    __syncthreads();
    float var = (red[0] + red[1] + red[2] + red[3]) * (1.f / 767.f);
    float inv = 1.f / (sqrtf(var) + 1e-6f);

    #pragma unroll
    for (int i = 0; i < 3; ++i) {
        int d = tid + i * 256;
        float y = gamma[d] * (x[i] - mean) * inv + beta[d];
        outb[base + d] = f2bu(y);
        outf[base + d] = y;
    }
}

// ---- LN2 (final): out = LN(ln1f + (f0+f1)); runtime out dtype -------------
__global__ __launch_bounds__(256) void ln2_kernel(
    const int* __restrict__ dflag,
    const float* __restrict__ a, const float* __restrict__ f0,
    const float* __restrict__ f1,
    const float* __restrict__ gamma, const float* __restrict__ beta,
    void* __restrict__ out)
{
    const int isf = dflag[0];
    const int row = blockIdx.x;
    const int tid = threadIdx.x;
    __shared__ float red[4];
    const size_t base = (size_t)row * 768;

    float x[3];
    #pragma unroll
    for (int i = 0; i < 3; ++i) {
        int d = tid + i * 256;
        x[i] = a[base + d] + f0[base + d] + f1[base + d];
    }

    float s = x[0] + x[1] + x[2];
    #pragma unroll
    for (int off = 32; off > 0; off >>= 1) s += __shfl_down(s, off, 64);
    if ((tid & 63) == 0) red[tid >> 6] = s;
    __syncthreads();
    float mean = (red[0] + red[1] + red[2] + red[3]) * (1.f / 768.f);
    __syncthreads();

    float vsum = 0.f;
    #pragma unroll
    for (int i = 0; i < 3; ++i) {
        float dd = x[i] - mean;
        vsum += dd * dd;
    }
    #pragma unroll
    for (int off = 32; off > 0; off >>= 1) vsum += __shfl_down(vsum, off, 64);
    if ((tid & 63) == 0) red[tid >> 6] = vsum;
    __syncthreads();
    float var = (red[0] + red[1] + red[2] + red[3]) * (1.f / 767.f);
    float inv = 1.f / (sqrtf(var) + 1e-6f);

    #pragma unroll
    for (int i = 0; i < 3; ++i) {
        int d = tid + i * 256;
        float y = gamma[d] * (x[i] - mean) * inv + beta[d];
        if (isf) ((float*)out)[base + d] = y;
        else     ((ushort*)out)[base + d] = f2bu(y);
    }
}

extern "C" void kernel_launch(void* const* d_in, const int* in_sizes, int n_in,
                              void* d_out, int out_size, void* d_ws, size_t ws_size,
                              hipStream_t stream) {
    const size_t nxd = 3145728;   // 4096*768
    char* base = (char*)d_ws;
    int* dflag = (int*)base;

    // workspace layout (round-10 verified, ~81MB):
    //  A: xb (bf16 x) -> later ln1b
    //  B: wall, vall
    //  C: qb|kb|vb|ctx (4*nxd bf16) -> ff1b
    //  D,E: f32 nxd (attn parts 0,1 -> oproj partials -> ff2 partials)
    //  G: f32 nxd (attn mlbuf; later ln1f)
    char* p = base + 256;
    ushort* xb   = (ushort*)p; p += nxd * 2;            // A
    ushort* wall = (ushort*)p; p += 7077888ull * 2;     // B
    float*  vall = (float*)p;  p += 40960;
    ushort* qb   = (ushort*)p;                          // C
    ushort* kb   = qb + nxd;
    ushort* vb   = kb + nxd;
    ushort* ctx  = vb + nxd;
    ushort* ff1b = qb;
    p += 4 * nxd * 2;
    float* dbuf = (float*)p; p += nxd * 4;              // D (part0)
    float* ebuf = (float*)p; p += nxd * 4;              // E (part1)
    float* gbuf = (float*)p; p += nxd * 4;              // G (mlbuf / ln1f)

    float* opart = dbuf;            // parts contiguous D,E
    float* mlbuf = gbuf;            // 786KB, dead before ln1f written
    ushort* ln1b = xb;              // xb dead after QKV
    float* ln1f = gbuf;

    const int* mask = (const int*)d_in[1];
    dim3 blk(256);

    detect_dtype_kernel<<<dim3(1), blk, 0, stream>>>(
        (const unsigned short*)d_in[0], dflag);

    conv_all_k<<<dim3(1024), blk, 0, stream>>>(dflag,
        d_in[0], d_in[2], d_in[4], d_in[6], d_in[8], d_in[10], d_in[12],
        d_in[3], d_in[5], d_in[7], d_in[9], d_in[11], d_in[13],
        d_in[14], d_in[15], d_in[16], d_in[17], xb, wall, vall);

    // QKV: M=4096, N=768 x3, K=768
    gemm_qkv_b<<<dim3(18, 32), blk, 0, stream>>>(xb, wall, vall, qb, kb, vb);

    // attention: split-K x2, 4-wave 64-row q-tiles (5 blocks/CU) + combine
    attn_mfma_b<<<dim3(1536), blk, 0, stream>>>(qb, kb, vb, mask, opart, mlbuf);
    attn_combine<<<dim3(4096), blk, 0, stream>>>(opart, mlbuf, ctx);

    // O-proj: M=4096, N=768, K=768, split-K x2 -> f32 partials D,E
    gemm_ksplit<64><<<dim3(6, 64, 2), blk, 0, stream>>>(
        ctx, wall + 1769472, vall + 2304, dbuf, 768, 768);

    ln1_kernel<<<dim3(4096), blk, 0, stream>>>(dflag,
        d_in[0], dbuf, ebuf, vall + 6912, vall + 7680, ln1b, ln1f);

    // FF1: M=4096, N=3072, K=768, relu -> bf16 (overwrites C)
    gemm_b<128><<<dim3(24, 32), blk, 0, stream>>>(
        ln1b, wall + 2359296, vall + 3072, ff1b, nullptr, 3072, 768, 1);

    // FF2: M=4096, N=768, K=3072, split-K x2 -> f32 partials D,E
    gemm_ksplit<64><<<dim3(6, 64, 2), blk, 0, stream>>>(
        ff1b, wall + 4718592, vall + 6144, dbuf, 768, 3072);

    ln2_kernel<<<dim3(4096), blk, 0, stream>>>(dflag,
        ln1f, dbuf, ebuf, vall + 8448, vall + 9216, d_out);
}

// Round 14
// 312.525 us; speedup vs baseline: 1.0450x; 1.0450x over previous
//
#include <hip/hip_runtime.h>
#include <hip/hip_bf16.h>

typedef __hip_bfloat16 bf16;
typedef unsigned short ushort;
typedef __attribute__((ext_vector_type(8))) short short8;  // 8 bf16 (4 VGPRs)
typedef __attribute__((ext_vector_type(4))) float f32x4;   // 4 fp32 acc

__device__ __forceinline__ float b2f(bf16 h) { return __bfloat162float(h); }
__device__ __forceinline__ bf16 f2b(float f) { return __float2bfloat16(f); }
__device__ __forceinline__ ushort f2bu(float f) {
    bf16 t = __float2bfloat16(f);
    ushort u;
    __builtin_memcpy(&u, &t, 2);
    return u;
}
__device__ __forceinline__ float bits2f(unsigned int u16) {
    unsigned int v = u16 << 16;
    float f;
    __builtin_memcpy(&f, &v, 4);
    return f;
}

// ---- async global->LDS (16B per lane; LDS dest is wave-uniform base) ------
__device__ __forceinline__ void gload16(const void* g, void* l) {
    __builtin_amdgcn_global_load_lds(
        (const __attribute__((address_space(1))) void*)g,
        (__attribute__((address_space(3))) void*)l, 16, 0, 0);
}

// ---- runtime dtype probe (proven) -----------------------------------------
__global__ void detect_dtype_kernel(const unsigned short* __restrict__ x,
                                    int* __restrict__ flag) {
    __shared__ int cnt;
    if (threadIdx.x == 0) cnt = 0;
    __syncthreads();
    int local = 0;
    for (int i = threadIdx.x; i < 2048; i += 256) {
        float v = bits2f((unsigned int)x[i]);
        if (!(fabsf(v) < 1e4f)) local++;  // also true for NaN/Inf
    }
    atomicAdd(&cnt, local);
    __syncthreads();
    if (threadIdx.x == 0) flag[0] = (cnt >= 8) ? 1 : 0;
}

// ---- 8-elem loader for either dtype (runtime flag) ------------------------
__device__ __forceinline__ void load8f_rt(const void* p, int isf, float* f) {
    if (isf) {
        const float* q = (const float*)p;
        float4 a = *(const float4*)q;
        float4 b = *(const float4*)(q + 4);
        f[0] = a.x; f[1] = a.y; f[2] = a.z; f[3] = a.w;
        f[4] = b.x; f[5] = b.y; f[6] = b.z; f[7] = b.w;
    } else {
        uint4 u = *(const uint4*)p;
        f[0] = bits2f(u.x & 0xffffu); f[1] = bits2f(u.x >> 16);
        f[2] = bits2f(u.y & 0xffffu); f[3] = bits2f(u.y >> 16);
        f[4] = bits2f(u.z & 0xffffu); f[5] = bits2f(u.z >> 16);
        f[6] = bits2f(u.w & 0xffffu); f[7] = bits2f(u.w >> 16);
    }
}
__device__ __forceinline__ float loadf_rt(const void* p, int isf, size_t i) {
    return isf ? ((const float*)p)[i] : bits2f(((const ushort*)p)[i]);
}

// ---- one-time conversion (single kernel, runtime dtype) -------------------
// wall layout (ushort): wq@0 wk@589824 wv@1179648 wo@1769472 w1@2359296 w2@4718592
// vall layout (float):  bq@0 bk@768 bv@1536 bo@2304 b1@3072 b2@6144
//                       g1@6912 be1@7680 g2@8448 be2@9216   (total 9984)
__global__ __launch_bounds__(256) void conv_all_k(
    const int* __restrict__ dflag,
    const void* __restrict__ x,
    const void* __restrict__ wq, const void* __restrict__ wk,
    const void* __restrict__ wv, const void* __restrict__ wo,
    const void* __restrict__ w1, const void* __restrict__ w2,
    const void* __restrict__ bq, const void* __restrict__ bk,
    const void* __restrict__ bv, const void* __restrict__ bo,
    const void* __restrict__ b1, const void* __restrict__ b2,
    const void* __restrict__ g1, const void* __restrict__ be1,
    const void* __restrict__ g2, const void* __restrict__ be2,
    ushort* __restrict__ xb, ushort* __restrict__ wall,
    float* __restrict__ vall)
{
    const int isf = dflag[0];
    const int esz = isf ? 4 : 2;
    const int gt = blockIdx.x * 256 + threadIdx.x;
    const int stride = gridDim.x * 256;

    // x -> bf16
    for (int v = gt; v < 393216; v += stride) {  // 3,145,728 / 8
        float f[8];
        load8f_rt((const char*)x + (size_t)v * 8 * esz, isf, f);
        unsigned int wd[4];
        #pragma unroll
        for (int i = 0; i < 4; ++i)
            wd[i] = (unsigned int)f2bu(f[2 * i]) | ((unsigned int)f2bu(f[2 * i + 1]) << 16);
        *(uint4*)(xb + (size_t)v * 8) = make_uint4(wd[0], wd[1], wd[2], wd[3]);
    }
    // weights -> bf16
    for (int v = gt; v < 884736; v += stride) {  // 7,077,888 / 8
        const void* src; int loc;
        if (v < 73728)        { src = wq; loc = v; }
        else if (v < 147456)  { src = wk; loc = v - 73728; }
        else if (v < 221184)  { src = wv; loc = v - 147456; }
        else if (v < 294912)  { src = wo; loc = v - 221184; }
        else if (v < 589824)  { src = w1; loc = v - 294912; }
        else                  { src = w2; loc = v - 589824; }
        float f[8];
        load8f_rt((const char*)src + (size_t)loc * 8 * esz, isf, f);
        unsigned int wd[4];
        #pragma unroll
        for (int i = 0; i < 4; ++i)
            wd[i] = (unsigned int)f2bu(f[2 * i]) | ((unsigned int)f2bu(f[2 * i + 1]) << 16);
        *(uint4*)(wall + (size_t)v * 8) = make_uint4(wd[0], wd[1], wd[2], wd[3]);
    }
    // vectors -> f32
    for (int i = gt; i < 9984; i += stride) {
        const void* s; int l;
        if (i < 768)       { s = bq;  l = i; }
        else if (i < 1536) { s = bk;  l = i - 768; }
        else if (i < 2304) { s = bv;  l = i - 1536; }
        else if (i < 3072) { s = bo;  l = i - 2304; }
        else if (i < 6144) { s = b1;  l = i - 3072; }
        else if (i < 6912) { s = b2;  l = i - 6144; }
        else if (i < 7680) { s = g1;  l = i - 6912; }
        else if (i < 8448) { s = be1; l = i - 7680; }
        else if (i < 9216) { s = g2;  l = i - 8448; }
        else               { s = be2; l = i - 9216; }
        vall[i] = loadf_rt(s, isf, l);
    }
}

// ========== bf16 MFMA GEMM, BK=64, XOR-swizzled LDS, 2-phase dbuf ==========
// (round-5 verified inner structure; K-range [kstart, kstart+klen) for
// split-K; nullable bias.)
// Frag layouts (m89-verified): A-frag m=lane&15, k=quad*8+j;
// B-frag n=lane&15, k=quad*8+j; C/D col=lane&15, row=quad*4+reg.
template <int BM>
__device__ __forceinline__ void gemm_bf16_body(
    const ushort* __restrict__ A, const ushort* __restrict__ Bw,
    const float* __restrict__ bias, ushort* __restrict__ Cb,
    float* __restrict__ Cf, int N, int K, int kstart, int klen,
    int bm, int bn, int relu)
{
    __shared__ __align__(16) ushort As[2][BM][64];   // [buf][m][k], 128B rows
    __shared__ __align__(16) ushort Bs[2][128][64];  // [buf][n][k]
    const int tid = threadIdx.x;
    const int w = tid >> 6, lane = tid & 63;
    const int quad = lane >> 4, l15 = lane & 15;
    constexpr int FM = BM / 32;                    // frags per wave in M
    const int wr = (w >> 1) * (BM / 2), wc = (w & 1) * 64;

    constexpr int CA = (BM * 128) / 4096;          // 4KB rounds for A tile
    constexpr int CB = 4;                          // 128*128B/4KB
    size_t aoff[CA]; int albase[CA];
    #pragma unroll
    for (int c = 0; c < CA; ++c) {
        int byte = c * 4096 + tid * 16;
        int row = byte >> 7, colb = byte & 127;
        int csrc = colb ^ ((row & 7) << 4);        // inverse swizzle on SOURCE
        aoff[c] = (size_t)(bm + row) * K + (csrc >> 1);
        albase[c] = c * 4096 + w * 1024;           // wave-uniform LDS base
    }
    size_t boff[CB]; int blbase[CB];
    #pragma unroll
    for (int c = 0; c < CB; ++c) {
        int byte = c * 4096 + tid * 16;
        int row = byte >> 7, colb = byte & 127;
        int csrc = colb ^ ((row & 7) << 4);
        boff[c] = (size_t)(bn + row) * K + (csrc >> 1);
        blbase[c] = c * 4096 + w * 1024;
    }

    f32x4 acc[FM][4];
    #pragma unroll
    for (int i = 0; i < FM; ++i)
        #pragma unroll
        for (int j = 0; j < 4; ++j) acc[i][j] = (f32x4){0.f, 0.f, 0.f, 0.f};

    constexpr int ASZ = BM * 128;      // bytes per A buffer
    constexpr int BSZ = 128 * 128;     // bytes per B buffer

#define STAGE(buf, k0)                                                        \
    {                                                                         \
        char* ab = (char*)As + (buf) * ASZ;                                   \
        char* bb = (char*)Bs + (buf) * BSZ;                                   \
        _Pragma("unroll")                                                     \
        for (int c = 0; c < CA; ++c)                                          \
            gload16(A + aoff[c] + (k0), ab + albase[c]);                      \
        _Pragma("unroll")                                                     \
        for (int c = 0; c < CB; ++c)                                          \
            gload16(Bw + boff[c] + (k0), bb + blbase[c]);                     \
    }

    const int NT = klen >> 6;
    STAGE(0, kstart);
    int cur = 0;
    for (int t = 0; t < NT; ++t) {
        __syncthreads();                 // buf[cur] visible (vmcnt drained)
        if (t + 1 < NT) STAGE(cur ^ 1, kstart + (t + 1) * 64);

        const ushort (*Asb)[64] = As[cur];
        const ushort (*Bsb)[64] = Bs[cur];
        short8 af[FM][2], bfr[4][2];
        #pragma unroll
        for (int i = 0; i < FM; ++i) {
            int r = wr + i * 16 + l15;
            int sw = (r & 7) << 3;                 // XOR key in ushort units
            af[i][0] = *(const short8*)&Asb[r][(quad * 8) ^ sw];
            af[i][1] = *(const short8*)&Asb[r][(32 + quad * 8) ^ sw];
        }
        #pragma unroll
        for (int j = 0; j < 4; ++j) {
            int r = wc + j * 16 + l15;
            int sw = (r & 7) << 3;
            bfr[j][0] = *(const short8*)&Bsb[r][(quad * 8) ^ sw];
            bfr[j][1] = *(const short8*)&Bsb[r][(32 + quad * 8) ^ sw];
        }
        #pragma unroll
        for (int h = 0; h < 2; ++h)
            #pragma unroll
            for (int i = 0; i < FM; ++i)
                #pragma unroll
                for (int j = 0; j < 4; ++j)
                    acc[i][j] = __builtin_amdgcn_mfma_f32_16x16x32_bf16(
                        af[i][h], bfr[j][h], acc[i][j], 0, 0, 0);
        cur ^= 1;
    }
#undef STAGE

    #pragma unroll
    for (int j = 0; j < 4; ++j) {
        int col = bn + wc + j * 16 + l15;
        float bv = bias ? bias[col] : 0.f;
        #pragma unroll
        for (int i = 0; i < FM; ++i) {
            int row0 = bm + wr + i * 16 + quad * 4;
            #pragma unroll
            for (int r = 0; r < 4; ++r) {
                float vv = acc[i][j][r] + bv;
                if (relu) vv = fmaxf(vv, 0.f);
                size_t idx = (size_t)(row0 + r) * N + col;
                if (Cb) Cb[idx] = f2bu(vv);
                if (Cf) Cf[idx] = vv;
            }
        }
    }
}

// XCD-aware bijective block swizzle (grids here are all %8 == 0)
__device__ __forceinline__ int xcd_swz(int bid, int nwg) {
    int cpx = nwg >> 3;
    return (bid & 7) * cpx + (bid >> 3);
}

template <int BM>
__global__ __launch_bounds__(256) void gemm_b(
    const ushort* __restrict__ A, const ushort* __restrict__ Bw,
    const float* __restrict__ bias, ushort* __restrict__ Cb,
    float* __restrict__ Cf, int N, int K, int relu)
{
    int nwg = gridDim.x * gridDim.y;
    int bid = xcd_swz(blockIdx.y * gridDim.x + blockIdx.x, nwg);
    int bx = bid % gridDim.x, by = bid / gridDim.x;
    gemm_bf16_body<BM>(A, Bw, bias, Cb, Cf, N, K, 0, K, by * BM, bx * 128, relu);
}

// split-K x2 GEMM: grid (nx, ny, 2); part z writes f32 partial Cf + z*nxd;
// bias added in part 0 only. LN kernels downstream sum the two partials.
template <int BM>
__global__ __launch_bounds__(256) void gemm_ksplit(
    const ushort* __restrict__ A, const ushort* __restrict__ Bw,
    const float* __restrict__ bias, float* __restrict__ Cf, int N, int K)
{
    const int part = blockIdx.z;
    int nwg = gridDim.x * gridDim.y;
    int bid = xcd_swz(blockIdx.y * gridDim.x + blockIdx.x, nwg);
    int bx = bid % gridDim.x, by = bid / gridDim.x;
    const int kh = K >> 1;
    gemm_bf16_body<BM>(A, Bw, part ? nullptr : bias, nullptr,
                       Cf + (size_t)part * 3145728, N, K,
                       part * kh, kh, by * BM, bx * 128, 0);
}

// Fused QKV: grid.x = 18 (3 mats x 6 n-tiles), grid.y = 32 (m-tiles)
__global__ __launch_bounds__(256) void gemm_qkv_b(
    const ushort* __restrict__ x, const ushort* __restrict__ wall,
    const float* __restrict__ vall,
    ushort* __restrict__ qb, ushort* __restrict__ kb, ushort* __restrict__ vb)
{
    int bid = xcd_swz(blockIdx.y * 18 + blockIdx.x, 576);
    int bx = bid % 18, by = bid / 18;
    const int mat = bx / 6;
    const int bn = (bx % 6) * 128;
    const ushort* W = wall + (size_t)mat * 589824;
    const float* Bi = vall + mat * 768;
    ushort* O = (mat == 0) ? qb : (mat == 1) ? kb : vb;
    gemm_bf16_body<128>(x, W, Bi, O, nullptr, 768, 768, 0, 768, by * 128, bn, 0);
}

// ============== bf16 MFMA flash attention, split-K x NP, 8-wave ============
// (round-9/10 verified core + T1 XCD-chunked swizzle; NP templated.)
// grid NP*384; part handles keys [part*(2048/NP), +2048/NP).
// NP=4 -> 8 K-tiles/part, grid 1536 (round-11 best-measured config).
template <int NP>
__global__ __launch_bounds__(512) void attn_mfma_b(
    const ushort* __restrict__ q, const ushort* __restrict__ k,
    const ushort* __restrict__ v, const int* __restrict__ mask,
    float* __restrict__ opart, float* __restrict__ mlbuf)
{
    const int S = 2048, D = 768;
    constexpr int SPK = 2048 / NP;   // keys per part
    constexpr int NT = SPK / 64;     // tiles per part
    const size_t NXD = 3145728;
    const float SC2 = 0.125f * 1.44269504088896f;   // score scale in log2 units
    __shared__ __align__(16) ushort Ks[64][72];     // [key][dim]
    __shared__ __align__(16) ushort Vt[64][72];     // [dim][key]
    __shared__ __align__(16) ushort Ps[8][16][72];  // per-wave P, XOR-swizzled
    __shared__ float mkAll[SPK];                    // additive mask bias (part)

    const int tid = threadIdx.x;
    const int w = tid >> 6, lane = tid & 63;
    const int quad = lane >> 4, l15 = lane & 15;

    // T1: XCD-chunked swizzle (bijective, NP*384 % 8 == 0)
    const int bx = xcd_swz(blockIdx.x, NP * 384);
    const int part = bx / 384;
    const int rest = bx - part * 384;
    const int q0 = (rest & 15) * 128;
    const int h = (rest >> 4) % 12;
    const int b = rest / 192;
    const int kbase = part * SPK;

    // hoist the part's mask flags once
    #pragma unroll
    for (int i = 0; i < SPK / 512; ++i) {
        int idx = tid + i * 512;
        mkAll[idx] = mask[b * S + kbase + idx] ? -30000.f : 0.f;
    }

    const size_t qrow = (size_t)(b * S + q0 + w * 16 + l15) * D + h * 64;
    const short8 aQ0 = *(const short8*)&q[qrow + quad * 8];
    const short8 aQ1 = *(const short8*)&q[qrow + 32 + quad * 8];

    short8 ones;
    #pragma unroll
    for (int j = 0; j < 8; ++j) ones[j] = (short)0x3F80;  // bf16 1.0

    f32x4 o[4], lacc;
    #pragma unroll
    for (int i = 0; i < 4; ++i) o[i] = (f32x4){0.f, 0.f, 0.f, 0.f};
    lacc = (f32x4){0.f, 0.f, 0.f, 0.f};
    float m_run = -3.0e38f;

    const int sr = tid >> 3;          // K staging: key row 0..63
    const int sc0 = (tid & 7) * 8;    // K staging: dim base (ushorts)

    const ushort* kp = k + (size_t)(b * S + kbase + sr) * D + h * 64 + sc0;
    const ushort* vp = v + (size_t)(b * S + kbase + lane) * D + h * 64 + w * 8;
    uint4 ka = *(const uint4*)kp;
    uint4 va = *(const uint4*)vp;

    for (int kt = 0; kt < NT; ++kt) {
        __syncthreads();  // previous tile's consumers done
        *(uint4*)&Ks[sr][sc0] = ka;
        {   // conflict-free transpose: wave w owns dims [w*8, w*8+8), lane=key
            alignas(16) ushort tmp[8];
            *(uint4*)tmp = va;
            #pragma unroll
            for (int i = 0; i < 8; ++i) Vt[w * 8 + i][lane] = tmp[i];
        }
        __syncthreads();  // tile visible

        // ---- prefetch next tile (flies under compute) ----
        if (kt + 1 < NT) {
            kp += 64 * D;
            vp += 64 * D;
            ka = *(const uint4*)kp;
            va = *(const uint4*)vp;
        }

        // ---- QK^T (log2 domain, additive mask) ----
        const float* mk = &mkAll[kt * 64];
        float scv[4][4];
        float vm = -3.0e38f;
        __builtin_amdgcn_s_setprio(1);
        #pragma unroll
        for (int s = 0; s < 4; ++s) {
            short8 bk0 = *(const short8*)&Ks[s * 16 + l15][quad * 8];
            short8 bk1 = *(const short8*)&Ks[s * 16 + l15][32 + quad * 8];
            f32x4 c = (f32x4){0.f, 0.f, 0.f, 0.f};
            c = __builtin_amdgcn_mfma_f32_16x16x32_bf16(aQ0, bk0, c, 0, 0, 0);
            c = __builtin_amdgcn_mfma_f32_16x16x32_bf16(aQ1, bk1, c, 0, 0, 0);
            float mb = mk[s * 16 + l15];
            #pragma unroll
            for (int r = 0; r < 4; ++r) {
                float val = __builtin_fmaf(c[r], SC2, mb);
                scv[s][r] = val;
                vm = fmaxf(vm, val);
            }
        }
        __builtin_amdgcn_s_setprio(0);
        // group max over keys (16 l15-lanes); shared by this quad's 4 q-rows
        vm = fmaxf(vm, __shfl_xor(vm, 1, 16));
        vm = fmaxf(vm, __shfl_xor(vm, 2, 16));
        vm = fmaxf(vm, __shfl_xor(vm, 4, 16));
        vm = fmaxf(vm, __shfl_xor(vm, 8, 16));

        // defer-max: rescale only when tile max grows past threshold
        if (__any(vm > m_run + 11.0f)) {
            float mn = fmaxf(m_run, vm);
            float alpha = exp2f(m_run - mn);
            #pragma unroll
            for (int s = 0; s < 4; ++s) o[s] *= alpha;
            lacc *= alpha;
            m_run = mn;
        }

        // P = exp2(scv - m_run) -> bf16, XOR-swizzled per-wave store
        #pragma unroll
        for (int r = 0; r < 4; ++r)
            #pragma unroll
            for (int s = 0; s < 4; ++s)
                Ps[w][quad * 4 + r][(s * 16 + l15) ^ (quad << 4)] =
                    f2bu(exp2f(scv[s][r] - m_run));
        asm volatile("s_waitcnt lgkmcnt(0)" ::: "memory");

        // ---- PV + l (ones column) ----
        {
            const int pswz = (l15 >> 2) << 4;
            short8 aP0 = *(const short8*)&Ps[w][l15][(quad * 8) ^ pswz];
            short8 aP1 = *(const short8*)&Ps[w][l15][(32 + quad * 8) ^ pswz];
            __builtin_amdgcn_s_setprio(1);
            lacc = __builtin_amdgcn_mfma_f32_16x16x32_bf16(aP0, ones, lacc, 0, 0, 0);
            lacc = __builtin_amdgcn_mfma_f32_16x16x32_bf16(aP1, ones, lacc, 0, 0, 0);
            #pragma unroll
            for (int s = 0; s < 4; ++s) {
                short8 bv0 = *(const short8*)&Vt[s * 16 + l15][quad * 8];
                short8 bv1 = *(const short8*)&Vt[s * 16 + l15][32 + quad * 8];
                o[s] = __builtin_amdgcn_mfma_f32_16x16x32_bf16(aP0, bv0, o[s], 0, 0, 0);
                o[s] = __builtin_amdgcn_mfma_f32_16x16x32_bf16(aP1, bv1, o[s], 0, 0, 0);
            }
            __builtin_amdgcn_s_setprio(0);
        }
    }

    // ---- epilogue: unnormalized f32 partial + (m,l) in log2 domain ----
    const size_t obase = (size_t)part * NXD +
                         (size_t)(b * S + q0 + w * 16) * D + h * 64;
    #pragma unroll
    for (int r = 0; r < 4; ++r)
        #pragma unroll
        for (int s = 0; s < 4; ++s)
            opart[obase + (size_t)(quad * 4 + r) * D + s * 16 + l15] = o[s][r];
    if (l15 == 0) {
        #pragma unroll
        for (int r = 0; r < 4; ++r) {
            int row = b * S + q0 + w * 16 + quad * 4 + r;
            size_t mi = (((size_t)part * 4096 + row) * 12 + h) * 2;
            mlbuf[mi] = m_run;
            mlbuf[mi + 1] = lacc[r];
        }
    }
}

// ---- combine NP split-K partials -> bf16 ctx (log2-domain m,l) ------------
template <int NP>
__global__ __launch_bounds__(256) void attn_combine(
    const float* __restrict__ opart, const float* __restrict__ mlbuf,
    ushort* __restrict__ ctx)
{
    const size_t NXD = 3145728;
    const int row = blockIdx.x;
    const int tid = threadIdx.x;
    #pragma unroll
    for (int i = 0; i < 3; ++i) {
        int d = tid + i * 256;
        int h = d >> 6;
        float mv[NP], lv[NP];
        float m = -3.0e38f;
        #pragma unroll
        for (int p = 0; p < NP; ++p) {
            size_t mi = (((size_t)p * 4096 + row) * 12 + h) * 2;
            mv[p] = mlbuf[mi];
            lv[p] = mlbuf[mi + 1];
            m = fmaxf(m, mv[p]);
        }
        size_t idx = (size_t)row * 768 + d;
        float den = 0.f, num = 0.f;
        #pragma unroll
        for (int p = 0; p < NP; ++p) {
            float e = exp2f(mv[p] - m);
            den += lv[p] * e;
            num += opart[(size_t)p * NXD + idx] * e;
        }
        ctx[idx] = f2bu(num / den);
    }
}

// ---- LN1: out = LN(x + (r0+r1)); runtime x dtype; bf16 + f32 out ----------
__global__ __launch_bounds__(256) void ln1_kernel(
    const int* __restrict__ dflag,
    const void* __restrict__ xa, const float* __restrict__ r0,
    const float* __restrict__ r1,
    const float* __restrict__ gamma, const float* __restrict__ beta,
    ushort* __restrict__ outb, float* __restrict__ outf)
{
    const int isf = dflag[0];
    const int row = blockIdx.x;
    const int tid = threadIdx.x;
    __shared__ float red[4];
    const size_t base = (size_t)row * 768;

    float x[3];
    #pragma unroll
    for (int i = 0; i < 3; ++i) {
        int d = tid + i * 256;
        x[i] = loadf_rt(xa, isf, base + d) + r0[base + d] + r1[base + d];
    }

    float s = x[0] + x[1] + x[2];
    #pragma unroll
    for (int off = 32; off > 0; off >>= 1) s += __shfl_down(s, off, 64);
    if ((tid & 63) == 0) red[tid >> 6] = s;
    __syncthreads();
    float mean = (red[0] + red[1] + red[2] + red[3]) * (1.f / 768.f);
    __syncthreads();

    float vsum = 0.f;
    #pragma unroll
    for (int i = 0; i < 3; ++i) {
        float dd = x[i] - mean;
        vsum += dd * dd;
    }
    #pragma unroll
    for (int off = 32; off > 0; off >>= 1) vsum += __shfl_down(vsum, off, 64);
    if ((tid & 63) == 0) red[tid >> 6] = vsum;
    __syncthreads();
    float var = (red[0] + red[1] + red[2] + red[3]) * (1.f / 767.f);
    float inv = 1.f / (sqrtf(var) + 1e-6f);

    #pragma unroll
    for (int i = 0; i < 3; ++i) {
        int d = tid + i * 256;
        float y = gamma[d] * (x[i] - mean) * inv + beta[d];
        outb[base + d] = f2bu(y);
        outf[base + d] = y;
    }
}

// ---- LN2 (final): out = LN(ln1f + (f0+f1)); runtime out dtype -------------
__global__ __launch_bounds__(256) void ln2_kernel(
    const int* __restrict__ dflag,
    const float* __restrict__ a, const float* __restrict__ f0,
    const float* __restrict__ f1,
    const float* __restrict__ gamma, const float* __restrict__ beta,
    void* __restrict__ out)
{
    const int isf = dflag[0];
    const int row = blockIdx.x;
    const int tid = threadIdx.x;
    __shared__ float red[4];
    const size_t base = (size_t)row * 768;

    float x[3];
    #pragma unroll
    for (int i = 0; i < 3; ++i) {
        int d = tid + i * 256;
        x[i] = a[base + d] + f0[base + d] + f1[base + d];
    }

    float s = x[0] + x[1] + x[2];
    #pragma unroll
    for (int off = 32; off > 0; off >>= 1) s += __shfl_down(s, off, 64);
    if ((tid & 63) == 0) red[tid >> 6] = s;
    __syncthreads();
    float mean = (red[0] + red[1] + red[2] + red[3]) * (1.f / 768.f);
    __syncthreads();

    float vsum = 0.f;
    #pragma unroll
    for (int i = 0; i < 3; ++i) {
        float dd = x[i] - mean;
        vsum += dd * dd;
    }
    #pragma unroll
    for (int off = 32; off > 0; off >>= 1) vsum += __shfl_down(vsum, off, 64);
    if ((tid & 63) == 0) red[tid >> 6] = vsum;
    __syncthreads();
    float var = (red[0] + red[1] + red[2] + red[3]) * (1.f / 767.f);
    float inv = 1.f / (sqrtf(var) + 1e-6f);

    #pragma unroll
    for (int i = 0; i < 3; ++i) {
        int d = tid + i * 256;
        float y = gamma[d] * (x[i] - mean) * inv + beta[d];
        if (isf) ((float*)out)[base + d] = y;
        else     ((ushort*)out)[base + d] = f2bu(y);
    }
}

extern "C" void kernel_launch(void* const* d_in, const int* in_sizes, int n_in,
                              void* d_out, int out_size, void* d_ws, size_t ws_size,
                              hipStream_t stream) {
    const size_t nxd = 3145728;   // 4096*768
    char* base = (char*)d_ws;
    int* dflag = (int*)base;

    // workspace layout:
    //  A: xb (bf16 x) -> later ln1b          6.3MB
    //  B: wall 14.2MB, vall 40KB
    //  C: qb|kb|vb|ctx (4*nxd bf16) -> ff1b  25.2MB
    //  D,E: f32 nxd each (attn parts 0,1 -> oproj partials -> ff2 partials)
    //  G: f32 nxd (attn mlbuf [split2] / part3 [split4]; later ln1f)
    //  F: f32 nxd (attn part2 [split4 only])
    //  M: mlbuf for split4 (1.6MB)
    // split2 high-water: ~81MB (round-10 verified). split4: ~94MB.
    char* p = base + 256;
    ushort* xb   = (ushort*)p; p += nxd * 2;            // A
    ushort* wall = (ushort*)p; p += 7077888ull * 2;     // B
    float*  vall = (float*)p;  p += 40960;
    ushort* qb   = (ushort*)p;                          // C
    ushort* kb   = qb + nxd;
    ushort* vb   = kb + nxd;
    ushort* ctx  = vb + nxd;
    ushort* ff1b = qb;
    p += 4 * nxd * 2;
    float* dbuf = (float*)p; p += nxd * 4;              // D (part0)
    float* ebuf = (float*)p; p += nxd * 4;              // E (part1)
    float* fbuf = (float*)p; p += nxd * 4;              // F (part2, split4)
    float* gbuf = (float*)p; p += nxd * 4;              // G (part3 / mlbuf2 / ln1f)
    float* mbuf = (float*)p; p += 4 * 4096 * 12 * 2 * 4;  // M (split4 mlbuf)
    size_t need4 = (size_t)((char*)(mbuf + 393216) - base);

    float* opart = dbuf;            // parts contiguous D,E,(F,G)
    ushort* ln1b = xb;              // xb dead after QKV
    float* ln1f = gbuf;             // written after attn partials consumed

    const int* mask = (const int*)d_in[1];
    dim3 blk(256);

    detect_dtype_kernel<<<dim3(1), blk, 0, stream>>>(
        (const unsigned short*)d_in[0], dflag);

    conv_all_k<<<dim3(1024), blk, 0, stream>>>(dflag,
        d_in[0], d_in[2], d_in[4], d_in[6], d_in[8], d_in[10], d_in[12],
        d_in[3], d_in[5], d_in[7], d_in[9], d_in[11], d_in[13],
        d_in[14], d_in[15], d_in[16], d_in[17], xb, wall, vall);

    // QKV: M=4096, N=768 x3, K=768
    gemm_qkv_b<<<dim3(18, 32), blk, 0, stream>>>(xb, wall, vall, qb, kb, vb);

    // attention: split-K x4 if workspace allows, else x2 (round-11 config)
    if (ws_size >= need4) {
        attn_mfma_b<4><<<dim3(1536), dim3(512), 0, stream>>>(
            qb, kb, vb, mask, opart, mbuf);
        attn_combine<4><<<dim3(4096), blk, 0, stream>>>(opart, mbuf, ctx);
    } else {
        attn_mfma_b<2><<<dim3(768), dim3(512), 0, stream>>>(
            qb, kb, vb, mask, opart, gbuf);
        attn_combine<2><<<dim3(4096), blk, 0, stream>>>(opart, gbuf, ctx);
    }

    // O-proj: M=4096, N=768, K=768, split-K x2 -> f32 partials D,E
    gemm_ksplit<64><<<dim3(6, 64, 2), blk, 0, stream>>>(
        ctx, wall + 1769472, vall + 2304, dbuf, 768, 768);

    ln1_kernel<<<dim3(4096), blk, 0, stream>>>(dflag,
        d_in[0], dbuf, ebuf, vall + 6912, vall + 7680, ln1b, ln1f);

    // FF1: M=4096, N=3072, K=768, relu -> bf16 (overwrites C)
    gemm_b<128><<<dim3(24, 32), blk, 0, stream>>>(
        ln1b, wall + 2359296, vall + 3072, ff1b, nullptr, 3072, 768, 1);

    // FF2: M=4096, N=768, K=3072, split-K x2 -> f32 partials D,E
    gemm_ksplit<64><<<dim3(6, 64, 2), blk, 0, stream>>>(
        ff1b, wall + 4718592, vall + 6144, dbuf, 768, 3072);

    ln2_kernel<<<dim3(4096), blk, 0, stream>>>(dflag,
        ln1f, dbuf, ebuf, vall + 8448, vall + 9216, d_out);
}

// Round 15
// 310.798 us; speedup vs baseline: 1.0508x; 1.0056x over previous
//
#include <hip/hip_runtime.h>
#include <hip/hip_bf16.h>

typedef __hip_bfloat16 bf16;
typedef unsigned short ushort;
typedef __attribute__((ext_vector_type(8))) short short8;  // 8 bf16 (4 VGPRs)
typedef __attribute__((ext_vector_type(4))) float f32x4;   // 4 fp32 acc

__device__ __forceinline__ float b2f(bf16 h) { return __bfloat162float(h); }
__device__ __forceinline__ bf16 f2b(float f) { return __float2bfloat16(f); }
__device__ __forceinline__ ushort f2bu(float f) {
    bf16 t = __float2bfloat16(f);
    ushort u;
    __builtin_memcpy(&u, &t, 2);
    return u;
}
__device__ __forceinline__ float bits2f(unsigned int u16) {
    unsigned int v = u16 << 16;
    float f;
    __builtin_memcpy(&f, &v, 4);
    return f;
}

// ---- async global->LDS (16B per lane; LDS dest is wave-uniform base) ------
__device__ __forceinline__ void gload16(const void* g, void* l) {
    __builtin_amdgcn_global_load_lds(
        (const __attribute__((address_space(1))) void*)g,
        (__attribute__((address_space(3))) void*)l, 16, 0, 0);
}

// ---- runtime dtype probe (proven) -----------------------------------------
__global__ void detect_dtype_kernel(const unsigned short* __restrict__ x,
                                    int* __restrict__ flag) {
    __shared__ int cnt;
    if (threadIdx.x == 0) cnt = 0;
    __syncthreads();
    int local = 0;
    for (int i = threadIdx.x; i < 2048; i += 256) {
        float v = bits2f((unsigned int)x[i]);
        if (!(fabsf(v) < 1e4f)) local++;  // also true for NaN/Inf
    }
    atomicAdd(&cnt, local);
    __syncthreads();
    if (threadIdx.x == 0) flag[0] = (cnt >= 8) ? 1 : 0;
}

// ---- 8-elem loader for either dtype (runtime flag) ------------------------
__device__ __forceinline__ void load8f_rt(const void* p, int isf, float* f) {
    if (isf) {
        const float* q = (const float*)p;
        float4 a = *(const float4*)q;
        float4 b = *(const float4*)(q + 4);
        f[0] = a.x; f[1] = a.y; f[2] = a.z; f[3] = a.w;
        f[4] = b.x; f[5] = b.y; f[6] = b.z; f[7] = b.w;
    } else {
        uint4 u = *(const uint4*)p;
        f[0] = bits2f(u.x & 0xffffu); f[1] = bits2f(u.x >> 16);
        f[2] = bits2f(u.y & 0xffffu); f[3] = bits2f(u.y >> 16);
        f[4] = bits2f(u.z & 0xffffu); f[5] = bits2f(u.z >> 16);
        f[6] = bits2f(u.w & 0xffffu); f[7] = bits2f(u.w >> 16);
    }
}
__device__ __forceinline__ float loadf_rt(const void* p, int isf, size_t i) {
    return isf ? ((const float*)p)[i] : bits2f(((const ushort*)p)[i]);
}

// ---- one-time conversion (single kernel, runtime dtype) -------------------
// wall layout (ushort): wq@0 wk@589824 wv@1179648 wo@1769472 w1@2359296 w2@4718592
// vall layout (float):  bq@0 bk@768 bv@1536 bo@2304 b1@3072 b2@6144
//                       g1@6912 be1@7680 g2@8448 be2@9216   (total 9984)
__global__ __launch_bounds__(256) void conv_all_k(
    const int* __restrict__ dflag,
    const void* __restrict__ x,
    const void* __restrict__ wq, const void* __restrict__ wk,
    const void* __restrict__ wv, const void* __restrict__ wo,
    const void* __restrict__ w1, const void* __restrict__ w2,
    const void* __restrict__ bq, const void* __restrict__ bk,
    const void* __restrict__ bv, const void* __restrict__ bo,
    const void* __restrict__ b1, const void* __restrict__ b2,
    const void* __restrict__ g1, const void* __restrict__ be1,
    const void* __restrict__ g2, const void* __restrict__ be2,
    ushort* __restrict__ xb, ushort* __restrict__ wall,
    float* __restrict__ vall)
{
    const int isf = dflag[0];
    const int esz = isf ? 4 : 2;
    const int gt = blockIdx.x * 256 + threadIdx.x;
    const int stride = gridDim.x * 256;

    // x -> bf16
    for (int v = gt; v < 393216; v += stride) {  // 3,145,728 / 8
        float f[8];
        load8f_rt((const char*)x + (size_t)v * 8 * esz, isf, f);
        unsigned int wd[4];
        #pragma unroll
        for (int i = 0; i < 4; ++i)
            wd[i] = (unsigned int)f2bu(f[2 * i]) | ((unsigned int)f2bu(f[2 * i + 1]) << 16);
        *(uint4*)(xb + (size_t)v * 8) = make_uint4(wd[0], wd[1], wd[2], wd[3]);
    }
    // weights -> bf16
    for (int v = gt; v < 884736; v += stride) {  // 7,077,888 / 8
        const void* src; int loc;
        if (v < 73728)        { src = wq; loc = v; }
        else if (v < 147456)  { src = wk; loc = v - 73728; }
        else if (v < 221184)  { src = wv; loc = v - 147456; }
        else if (v < 294912)  { src = wo; loc = v - 221184; }
        else if (v < 589824)  { src = w1; loc = v - 294912; }
        else                  { src = w2; loc = v - 589824; }
        float f[8];
        load8f_rt((const char*)src + (size_t)loc * 8 * esz, isf, f);
        unsigned int wd[4];
        #pragma unroll
        for (int i = 0; i < 4; ++i)
            wd[i] = (unsigned int)f2bu(f[2 * i]) | ((unsigned int)f2bu(f[2 * i + 1]) << 16);
        *(uint4*)(wall + (size_t)v * 8) = make_uint4(wd[0], wd[1], wd[2], wd[3]);
    }
    // vectors -> f32
    for (int i = gt; i < 9984; i += stride) {
        const void* s; int l;
        if (i < 768)       { s = bq;  l = i; }
        else if (i < 1536) { s = bk;  l = i - 768; }
        else if (i < 2304) { s = bv;  l = i - 1536; }
        else if (i < 3072) { s = bo;  l = i - 2304; }
        else if (i < 6144) { s = b1;  l = i - 3072; }
        else if (i < 6912) { s = b2;  l = i - 6144; }
        else if (i < 7680) { s = g1;  l = i - 6912; }
        else if (i < 8448) { s = be1; l = i - 7680; }
        else if (i < 9216) { s = g2;  l = i - 8448; }
        else               { s = be2; l = i - 9216; }
        vall[i] = loadf_rt(s, isf, l);
    }
}

// ========== bf16 MFMA GEMM, BK=64, XOR-swizzled LDS, 2-phase dbuf ==========
// (round-5 verified inner structure; K-range [kstart, kstart+klen) for
// split-K; nullable bias.)
// Frag layouts (m89-verified): A-frag m=lane&15, k=quad*8+j;
// B-frag n=lane&15, k=quad*8+j; C/D col=lane&15, row=quad*4+reg.
template <int BM>
__device__ __forceinline__ void gemm_bf16_body(
    const ushort* __restrict__ A, const ushort* __restrict__ Bw,
    const float* __restrict__ bias, ushort* __restrict__ Cb,
    float* __restrict__ Cf, int N, int K, int kstart, int klen,
    int bm, int bn, int relu)
{
    __shared__ __align__(16) ushort As[2][BM][64];   // [buf][m][k], 128B rows
    __shared__ __align__(16) ushort Bs[2][128][64];  // [buf][n][k]
    const int tid = threadIdx.x;
    const int w = tid >> 6, lane = tid & 63;
    const int quad = lane >> 4, l15 = lane & 15;
    constexpr int FM = BM / 32;                    // frags per wave in M
    const int wr = (w >> 1) * (BM / 2), wc = (w & 1) * 64;

    constexpr int CA = (BM * 128) / 4096;          // 4KB rounds for A tile
    constexpr int CB = 4;                          // 128*128B/4KB
    size_t aoff[CA]; int albase[CA];
    #pragma unroll
    for (int c = 0; c < CA; ++c) {
        int byte = c * 4096 + tid * 16;
        int row = byte >> 7, colb = byte & 127;
        int csrc = colb ^ ((row & 7) << 4);        // inverse swizzle on SOURCE
        aoff[c] = (size_t)(bm + row) * K + (csrc >> 1);
        albase[c] = c * 4096 + w * 1024;           // wave-uniform LDS base
    }
    size_t boff[CB]; int blbase[CB];
    #pragma unroll
    for (int c = 0; c < CB; ++c) {
        int byte = c * 4096 + tid * 16;
        int row = byte >> 7, colb = byte & 127;
        int csrc = colb ^ ((row & 7) << 4);
        boff[c] = (size_t)(bn + row) * K + (csrc >> 1);
        blbase[c] = c * 4096 + w * 1024;
    }

    f32x4 acc[FM][4];
    #pragma unroll
    for (int i = 0; i < FM; ++i)
        #pragma unroll
        for (int j = 0; j < 4; ++j) acc[i][j] = (f32x4){0.f, 0.f, 0.f, 0.f};

    constexpr int ASZ = BM * 128;      // bytes per A buffer
    constexpr int BSZ = 128 * 128;     // bytes per B buffer

#define STAGE(buf, k0)                                                        \
    {                                                                         \
        char* ab = (char*)As + (buf) * ASZ;                                   \
        char* bb = (char*)Bs + (buf) * BSZ;                                   \
        _Pragma("unroll")                                                     \
        for (int c = 0; c < CA; ++c)                                          \
            gload16(A + aoff[c] + (k0), ab + albase[c]);                      \
        _Pragma("unroll")                                                     \
        for (int c = 0; c < CB; ++c)                                          \
            gload16(Bw + boff[c] + (k0), bb + blbase[c]);                     \
    }

    const int NT = klen >> 6;
    STAGE(0, kstart);
    int cur = 0;
    for (int t = 0; t < NT; ++t) {
        __syncthreads();                 // buf[cur] visible (vmcnt drained)
        if (t + 1 < NT) STAGE(cur ^ 1, kstart + (t + 1) * 64);

        const ushort (*Asb)[64] = As[cur];
        const ushort (*Bsb)[64] = Bs[cur];
        short8 af[FM][2], bfr[4][2];
        #pragma unroll
        for (int i = 0; i < FM; ++i) {
            int r = wr + i * 16 + l15;
            int sw = (r & 7) << 3;                 // XOR key in ushort units
            af[i][0] = *(const short8*)&Asb[r][(quad * 8) ^ sw];
            af[i][1] = *(const short8*)&Asb[r][(32 + quad * 8) ^ sw];
        }
        #pragma unroll
        for (int j = 0; j < 4; ++j) {
            int r = wc + j * 16 + l15;
            int sw = (r & 7) << 3;
            bfr[j][0] = *(const short8*)&Bsb[r][(quad * 8) ^ sw];
            bfr[j][1] = *(const short8*)&Bsb[r][(32 + quad * 8) ^ sw];
        }
        #pragma unroll
        for (int h = 0; h < 2; ++h)
            #pragma unroll
            for (int i = 0; i < FM; ++i)
                #pragma unroll
                for (int j = 0; j < 4; ++j)
                    acc[i][j] = __builtin_amdgcn_mfma_f32_16x16x32_bf16(
                        af[i][h], bfr[j][h], acc[i][j], 0, 0, 0);
        cur ^= 1;
    }
#undef STAGE

    #pragma unroll
    for (int j = 0; j < 4; ++j) {
        int col = bn + wc + j * 16 + l15;
        float bv = bias ? bias[col] : 0.f;
        #pragma unroll
        for (int i = 0; i < FM; ++i) {
            int row0 = bm + wr + i * 16 + quad * 4;
            #pragma unroll
            for (int r = 0; r < 4; ++r) {
                float vv = acc[i][j][r] + bv;
                if (relu) vv = fmaxf(vv, 0.f);
                size_t idx = (size_t)(row0 + r) * N + col;
                if (Cb) Cb[idx] = f2bu(vv);
                if (Cf) Cf[idx] = vv;
            }
        }
    }
}

// XCD-aware bijective block swizzle (grids here are all %8 == 0)
__device__ __forceinline__ int xcd_swz(int bid, int nwg) {
    int cpx = nwg >> 3;
    return (bid & 7) * cpx + (bid >> 3);
}

template <int BM>
__global__ __launch_bounds__(256) void gemm_b(
    const ushort* __restrict__ A, const ushort* __restrict__ Bw,
    const float* __restrict__ bias, ushort* __restrict__ Cb,
    float* __restrict__ Cf, int N, int K, int relu)
{
    int nwg = gridDim.x * gridDim.y;
    int bid = xcd_swz(blockIdx.y * gridDim.x + blockIdx.x, nwg);
    int bx = bid % gridDim.x, by = bid / gridDim.x;
    gemm_bf16_body<BM>(A, Bw, bias, Cb, Cf, N, K, 0, K, by * BM, bx * 128, relu);
}

// split-K x2 GEMM: grid (nx, ny, 2); part z writes f32 partial Cf + z*nxd;
// bias added in part 0 only. LN kernels downstream sum the two partials.
template <int BM>
__global__ __launch_bounds__(256) void gemm_ksplit(
    const ushort* __restrict__ A, const ushort* __restrict__ Bw,
    const float* __restrict__ bias, float* __restrict__ Cf, int N, int K)
{
    const int part = blockIdx.z;
    int nwg = gridDim.x * gridDim.y;
    int bid = xcd_swz(blockIdx.y * gridDim.x + blockIdx.x, nwg);
    int bx = bid % gridDim.x, by = bid / gridDim.x;
    const int kh = K >> 1;
    gemm_bf16_body<BM>(A, Bw, part ? nullptr : bias, nullptr,
                       Cf + (size_t)part * 3145728, N, K,
                       part * kh, kh, by * BM, bx * 128, 0);
}

// Fused QKV: BM=64 this round (48KB LDS -> 3 blocks/CU vs 2 at BM=128).
// grid.x = 18 (3 mats x 6 n-tiles), grid.y = 64 (m-tiles of 64 rows)
__global__ __launch_bounds__(256) void gemm_qkv_b(
    const ushort* __restrict__ x, const ushort* __restrict__ wall,
    const float* __restrict__ vall,
    ushort* __restrict__ qb, ushort* __restrict__ kb, ushort* __restrict__ vb)
{
    int bid = xcd_swz(blockIdx.y * 18 + blockIdx.x, 1152);
    int bx = bid % 18, by = bid / 18;
    const int mat = bx / 6;
    const int bn = (bx % 6) * 128;
    const ushort* W = wall + (size_t)mat * 589824;
    const float* Bi = vall + mat * 768;
    ushort* O = (mat == 0) ? qb : (mat == 1) ? kb : vb;
    gemm_bf16_body<64>(x, W, Bi, O, nullptr, 768, 768, 0, 768, by * 64, bn, 0);
}

// ============== bf16 MFMA flash attention, split-K x NP, 8-wave ============
// (round-9/10 verified core + T1 XCD-chunked swizzle; NP templated.)
// grid NP*384; part handles keys [part*(2048/NP), +2048/NP).
// NP=4 -> 8 K-tiles/part, grid 1536 (round-11/14 best-measured config).
template <int NP>
__global__ __launch_bounds__(512) void attn_mfma_b(
    const ushort* __restrict__ q, const ushort* __restrict__ k,
    const ushort* __restrict__ v, const int* __restrict__ mask,
    float* __restrict__ opart, float* __restrict__ mlbuf)
{
    const int S = 2048, D = 768;
    constexpr int SPK = 2048 / NP;   // keys per part
    constexpr int NT = SPK / 64;     // tiles per part
    const size_t NXD = 3145728;
    const float SC2 = 0.125f * 1.44269504088896f;   // score scale in log2 units
    __shared__ __align__(16) ushort Ks[64][72];     // [key][dim]
    __shared__ __align__(16) ushort Vt[64][72];     // [dim][key]
    __shared__ __align__(16) ushort Ps[8][16][72];  // per-wave P, XOR-swizzled
    __shared__ float mkAll[SPK];                    // additive mask bias (part)

    const int tid = threadIdx.x;
    const int w = tid >> 6, lane = tid & 63;
    const int quad = lane >> 4, l15 = lane & 15;

    // T1: XCD-chunked swizzle (bijective, NP*384 % 8 == 0)
    const int bx = xcd_swz(blockIdx.x, NP * 384);
    const int part = bx / 384;
    const int rest = bx - part * 384;
    const int q0 = (rest & 15) * 128;
    const int h = (rest >> 4) % 12;
    const int b = rest / 192;
    const int kbase = part * SPK;

    // hoist the part's mask flags once
    #pragma unroll
    for (int i = 0; i < SPK / 512; ++i) {
        int idx = tid + i * 512;
        mkAll[idx] = mask[b * S + kbase + idx] ? -30000.f : 0.f;
    }

    const size_t qrow = (size_t)(b * S + q0 + w * 16 + l15) * D + h * 64;
    const short8 aQ0 = *(const short8*)&q[qrow + quad * 8];
    const short8 aQ1 = *(const short8*)&q[qrow + 32 + quad * 8];

    short8 ones;
    #pragma unroll
    for (int j = 0; j < 8; ++j) ones[j] = (short)0x3F80;  // bf16 1.0

    f32x4 o[4], lacc;
    #pragma unroll
    for (int i = 0; i < 4; ++i) o[i] = (f32x4){0.f, 0.f, 0.f, 0.f};
    lacc = (f32x4){0.f, 0.f, 0.f, 0.f};
    float m_run = -3.0e38f;

    const int sr = tid >> 3;          // K staging: key row 0..63
    const int sc0 = (tid & 7) * 8;    // K staging: dim base (ushorts)

    const ushort* kp = k + (size_t)(b * S + kbase + sr) * D + h * 64 + sc0;
    const ushort* vp = v + (size_t)(b * S + kbase + lane) * D + h * 64 + w * 8;
    uint4 ka = *(const uint4*)kp;
    uint4 va = *(const uint4*)vp;

    for (int kt = 0; kt < NT; ++kt) {
        __syncthreads();  // previous tile's consumers done
        *(uint4*)&Ks[sr][sc0] = ka;
        {   // conflict-free transpose: wave w owns dims [w*8, w*8+8), lane=key
            alignas(16) ushort tmp[8];
            *(uint4*)tmp = va;
            #pragma unroll
            for (int i = 0; i < 8; ++i) Vt[w * 8 + i][lane] = tmp[i];
        }
        __syncthreads();  // tile visible

        // ---- prefetch next tile (flies under compute) ----
        if (kt + 1 < NT) {
            kp += 64 * D;
            vp += 64 * D;
            ka = *(const uint4*)kp;
            va = *(const uint4*)vp;
        }

        // ---- QK^T (log2 domain, additive mask) ----
        const float* mk = &mkAll[kt * 64];
        float scv[4][4];
        float vm = -3.0e38f;
        __builtin_amdgcn_s_setprio(1);
        #pragma unroll
        for (int s = 0; s < 4; ++s) {
            short8 bk0 = *(const short8*)&Ks[s * 16 + l15][quad * 8];
            short8 bk1 = *(const short8*)&Ks[s * 16 + l15][32 + quad * 8];
            f32x4 c = (f32x4){0.f, 0.f, 0.f, 0.f};
            c = __builtin_amdgcn_mfma_f32_16x16x32_bf16(aQ0, bk0, c, 0, 0, 0);
            c = __builtin_amdgcn_mfma_f32_16x16x32_bf16(aQ1, bk1, c, 0, 0, 0);
            float mb = mk[s * 16 + l15];
            #pragma unroll
            for (int r = 0; r < 4; ++r) {
                float val = __builtin_fmaf(c[r], SC2, mb);
                scv[s][r] = val;
                vm = fmaxf(vm, val);
            }
        }
        __builtin_amdgcn_s_setprio(0);
        // group max over keys (16 l15-lanes); shared by this quad's 4 q-rows
        vm = fmaxf(vm, __shfl_xor(vm, 1, 16));
        vm = fmaxf(vm, __shfl_xor(vm, 2, 16));
        vm = fmaxf(vm, __shfl_xor(vm, 4, 16));
        vm = fmaxf(vm, __shfl_xor(vm, 8, 16));

        // defer-max: rescale only when tile max grows past threshold
        if (__any(vm > m_run + 11.0f)) {
            float mn = fmaxf(m_run, vm);
            float alpha = exp2f(m_run - mn);
            #pragma unroll
            for (int s = 0; s < 4; ++s) o[s] *= alpha;
            lacc *= alpha;
            m_run = mn;
        }

        // P = exp2(scv - m_run) -> bf16, XOR-swizzled per-wave store
        #pragma unroll
        for (int r = 0; r < 4; ++r)
            #pragma unroll
            for (int s = 0; s < 4; ++s)
                Ps[w][quad * 4 + r][(s * 16 + l15) ^ (quad << 4)] =
                    f2bu(exp2f(scv[s][r] - m_run));
        asm volatile("s_waitcnt lgkmcnt(0)" ::: "memory");

        // ---- PV + l (ones column) ----
        {
            const int pswz = (l15 >> 2) << 4;
            short8 aP0 = *(const short8*)&Ps[w][l15][(quad * 8) ^ pswz];
            short8 aP1 = *(const short8*)&Ps[w][l15][(32 + quad * 8) ^ pswz];
            __builtin_amdgcn_s_setprio(1);
            lacc = __builtin_amdgcn_mfma_f32_16x16x32_bf16(aP0, ones, lacc, 0, 0, 0);
            lacc = __builtin_amdgcn_mfma_f32_16x16x32_bf16(aP1, ones, lacc, 0, 0, 0);
            #pragma unroll
            for (int s = 0; s < 4; ++s) {
                short8 bv0 = *(const short8*)&Vt[s * 16 + l15][quad * 8];
                short8 bv1 = *(const short8*)&Vt[s * 16 + l15][32 + quad * 8];
                o[s] = __builtin_amdgcn_mfma_f32_16x16x32_bf16(aP0, bv0, o[s], 0, 0, 0);
                o[s] = __builtin_amdgcn_mfma_f32_16x16x32_bf16(aP1, bv1, o[s], 0, 0, 0);
            }
            __builtin_amdgcn_s_setprio(0);
        }
    }

    // ---- epilogue: unnormalized f32 partial + (m,l) in log2 domain ----
    const size_t obase = (size_t)part * NXD +
                         (size_t)(b * S + q0 + w * 16) * D + h * 64;
    #pragma unroll
    for (int r = 0; r < 4; ++r)
        #pragma unroll
        for (int s = 0; s < 4; ++s)
            opart[obase + (size_t)(quad * 4 + r) * D + s * 16 + l15] = o[s][r];
    if (l15 == 0) {
        #pragma unroll
        for (int r = 0; r < 4; ++r) {
            int row = b * S + q0 + w * 16 + quad * 4 + r;
            size_t mi = (((size_t)part * 4096 + row) * 12 + h) * 2;
            mlbuf[mi] = m_run;
            mlbuf[mi + 1] = lacc[r];
        }
    }
}

// ---- combine NP split-K partials -> bf16 ctx (log2-domain m,l) ------------
template <int NP>
__global__ __launch_bounds__(256) void attn_combine(
    const float* __restrict__ opart, const float* __restrict__ mlbuf,
    ushort* __restrict__ ctx)
{
    const size_t NXD = 3145728;
    const int row = blockIdx.x;
    const int tid = threadIdx.x;
    #pragma unroll
    for (int i = 0; i < 3; ++i) {
        int d = tid + i * 256;
        int h = d >> 6;
        float mv[NP], lv[NP];
        float m = -3.0e38f;
        #pragma unroll
        for (int p = 0; p < NP; ++p) {
            size_t mi = (((size_t)p * 4096 + row) * 12 + h) * 2;
            mv[p] = mlbuf[mi];
            lv[p] = mlbuf[mi + 1];
            m = fmaxf(m, mv[p]);
        }
        size_t idx = (size_t)row * 768 + d;
        float den = 0.f, num = 0.f;
        #pragma unroll
        for (int p = 0; p < NP; ++p) {
            float e = exp2f(mv[p] - m);
            den += lv[p] * e;
            num += opart[(size_t)p * NXD + idx] * e;
        }
        ctx[idx] = f2bu(num / den);
    }
}

// ---- LN1: out = LN(x + (r0+r1)); runtime x dtype; bf16 + f32 out ----------
__global__ __launch_bounds__(256) void ln1_kernel(
    const int* __restrict__ dflag,
    const void* __restrict__ xa, const float* __restrict__ r0,
    const float* __restrict__ r1,
    const float* __restrict__ gamma, const float* __restrict__ beta,
    ushort* __restrict__ outb, float* __restrict__ outf)
{
    const int isf = dflag[0];
    const int row = blockIdx.x;
    const int tid = threadIdx.x;
    __shared__ float red[4];
    const size_t base = (size_t)row * 768;

    float x[3];
    #pragma unroll
    for (int i = 0; i < 3; ++i) {
        int d = tid + i * 256;
        x[i] = loadf_rt(xa, isf, base + d) + r0[base + d] + r1[base + d];
    }

    float s = x[0] + x[1] + x[2];
    #pragma unroll
    for (int off = 32; off > 0; off >>= 1) s += __shfl_down(s, off, 64);
    if ((tid & 63) == 0) red[tid >> 6] = s;
    __syncthreads();
    float mean = (red[0] + red[1] + red[2] + red[3]) * (1.f / 768.f);
    __syncthreads();

    float vsum = 0.f;
    #pragma unroll
    for (int i = 0; i < 3; ++i) {
        float dd = x[i] - mean;
        vsum += dd * dd;
    }
    #pragma unroll
    for (int off = 32; off > 0; off >>= 1) vsum += __shfl_down(vsum, off, 64);
    if ((tid & 63) == 0) red[tid >> 6] = vsum;
    __syncthreads();
    float var = (red[0] + red[1] + red[2] + red[3]) * (1.f / 767.f);
    float inv = 1.f / (sqrtf(var) + 1e-6f);

    #pragma unroll
    for (int i = 0; i < 3; ++i) {
        int d = tid + i * 256;
        float y = gamma[d] * (x[i] - mean) * inv + beta[d];
        outb[base + d] = f2bu(y);
        outf[base + d] = y;
    }
}

// ---- LN2 (final): out = LN(ln1f + (f0+f1)); runtime out dtype -------------
__global__ __launch_bounds__(256) void ln2_kernel(
    const int* __restrict__ dflag,
    const float* __restrict__ a, const float* __restrict__ f0,
    const float* __restrict__ f1,
    const float* __restrict__ gamma, const float* __restrict__ beta,
    void* __restrict__ out)
{
    const int isf = dflag[0];
    const int row = blockIdx.x;
    const int tid = threadIdx.x;
    __shared__ float red[4];
    const size_t base = (size_t)row * 768;

    float x[3];
    #pragma unroll
    for (int i = 0; i < 3; ++i) {
        int d = tid + i * 256;
        x[i] = a[base + d] + f0[base + d] + f1[base + d];
    }

    float s = x[0] + x[1] + x[2];
    #pragma unroll
    for (int off = 32; off > 0; off >>= 1) s += __shfl_down(s, off, 64);
    if ((tid & 63) == 0) red[tid >> 6] = s;
    __syncthreads();
    float mean = (red[0] + red[1] + red[2] + red[3]) * (1.f / 768.f);
    __syncthreads();

    float vsum = 0.f;
    #pragma unroll
    for (int i = 0; i < 3; ++i) {
        float dd = x[i] - mean;
        vsum += dd * dd;
    }
    #pragma unroll
    for (int off = 32; off > 0; off >>= 1) vsum += __shfl_down(vsum, off, 64);
    if ((tid & 63) == 0) red[tid >> 6] = vsum;
    __syncthreads();
    float var = (red[0] + red[1] + red[2] + red[3]) * (1.f / 767.f);
    float inv = 1.f / (sqrtf(var) + 1e-6f);

    #pragma unroll
    for (int i = 0; i < 3; ++i) {
        int d = tid + i * 256;
        float y = gamma[d] * (x[i] - mean) * inv + beta[d];
        if (isf) ((float*)out)[base + d] = y;
        else     ((ushort*)out)[base + d] = f2bu(y);
    }
}

extern "C" void kernel_launch(void* const* d_in, const int* in_sizes, int n_in,
                              void* d_out, int out_size, void* d_ws, size_t ws_size,
                              hipStream_t stream) {
    const size_t nxd = 3145728;   // 4096*768
    char* base = (char*)d_ws;
    int* dflag = (int*)base;

    // workspace layout:
    //  A: xb (bf16 x) -> later ln1b          6.3MB
    //  B: wall 14.2MB, vall 40KB
    //  C: qb|kb|vb|ctx (4*nxd bf16) -> ff1b  25.2MB
    //  D,E: f32 nxd each (attn parts 0,1 -> oproj partials -> ff2 partials)
    //  G: f32 nxd (attn mlbuf [split2] / part3 [split4]; later ln1f)
    //  F: f32 nxd (attn part2 [split4 only])
    //  M: mlbuf for split4 (1.6MB)
    char* p = base + 256;
    ushort* xb   = (ushort*)p; p += nxd * 2;            // A
    ushort* wall = (ushort*)p; p += 7077888ull * 2;     // B
    float*  vall = (float*)p;  p += 40960;
    ushort* qb   = (ushort*)p;                          // C
    ushort* kb   = qb + nxd;
    ushort* vb   = kb + nxd;
    ushort* ctx  = vb + nxd;
    ushort* ff1b = qb;
    p += 4 * nxd * 2;
    float* dbuf = (float*)p; p += nxd * 4;              // D (part0)
    float* ebuf = (float*)p; p += nxd * 4;              // E (part1)
    float* fbuf = (float*)p; p += nxd * 4;              // F (part2, split4)
    float* gbuf = (float*)p; p += nxd * 4;              // G (part3 / mlbuf2 / ln1f)
    float* mbuf = (float*)p; p += 4 * 4096 * 12 * 2 * 4;  // M (split4 mlbuf)
    size_t need4 = (size_t)((char*)(mbuf + 393216) - base);

    float* opart = dbuf;            // parts contiguous D,E,(F,G)
    ushort* ln1b = xb;              // xb dead after QKV
    float* ln1f = gbuf;             // written after attn partials consumed

    const int* mask = (const int*)d_in[1];
    dim3 blk(256);

    detect_dtype_kernel<<<dim3(1), blk, 0, stream>>>(
        (const unsigned short*)d_in[0], dflag);

    conv_all_k<<<dim3(1024), blk, 0, stream>>>(dflag,
        d_in[0], d_in[2], d_in[4], d_in[6], d_in[8], d_in[10], d_in[12],
        d_in[3], d_in[5], d_in[7], d_in[9], d_in[11], d_in[13],
        d_in[14], d_in[15], d_in[16], d_in[17], xb, wall, vall);

    // QKV: M=4096, N=768 x3, K=768; BM=64 -> 1152 blocks (3 blocks/CU)
    gemm_qkv_b<<<dim3(18, 64), blk, 0, stream>>>(xb, wall, vall, qb, kb, vb);

    // attention: split-K x4 if workspace allows, else x2 (round-11 config)
    if (ws_size >= need4) {
        attn_mfma_b<4><<<dim3(1536), dim3(512), 0, stream>>>(
            qb, kb, vb, mask, opart, mbuf);
        attn_combine<4><<<dim3(4096), blk, 0, stream>>>(opart, mbuf, ctx);
    } else {
        attn_mfma_b<2><<<dim3(768), dim3(512), 0, stream>>>(
            qb, kb, vb, mask, opart, gbuf);
        attn_combine<2><<<dim3(4096), blk, 0, stream>>>(opart, gbuf, ctx);
    }

    // O-proj: M=4096, N=768, K=768, split-K x2 -> f32 partials D,E
    gemm_ksplit<64><<<dim3(6, 64, 2), blk, 0, stream>>>(
        ctx, wall + 1769472, vall + 2304, dbuf, 768, 768);

    ln1_kernel<<<dim3(4096), blk, 0, stream>>>(dflag,
        d_in[0], dbuf, ebuf, vall + 6912, vall + 7680, ln1b, ln1f);

    // FF1: M=4096, N=3072, K=768, relu -> bf16; BM=64 -> 1536 blocks (3/CU)
    gemm_b<64><<<dim3(24, 64), blk, 0, stream>>>(
        ln1b, wall + 2359296, vall + 3072, ff1b, nullptr, 3072, 768, 1);

    // FF2: M=4096, N=768, K=3072, split-K x2 -> f32 partials D,E
    gemm_ksplit<64><<<dim3(6, 64, 2), blk, 0, stream>>>(
        ff1b, wall + 4718592, vall + 6144, dbuf, 768, 3072);

    ln2_kernel<<<dim3(4096), blk, 0, stream>>>(dflag,
        ln1f, dbuf, ebuf, vall + 8448, vall + 9216, d_out);
}

// Round 16
// 306.918 us; speedup vs baseline: 1.0641x; 1.0126x over previous
//
#include <hip/hip_runtime.h>
#include <hip/hip_bf16.h>

typedef __hip_bfloat16 bf16;
typedef unsigned short ushort;
typedef __attribute__((ext_vector_type(8))) short short8;  // 8 bf16 (4 VGPRs)
typedef __attribute__((ext_vector_type(4))) float f32x4;   // 4 fp32 acc

__device__ __forceinline__ float b2f(bf16 h) { return __bfloat162float(h); }
__device__ __forceinline__ bf16 f2b(float f) { return __float2bfloat16(f); }
__device__ __forceinline__ ushort f2bu(float f) {
    bf16 t = __float2bfloat16(f);
    ushort u;
    __builtin_memcpy(&u, &t, 2);
    return u;
}
__device__ __forceinline__ float bits2f(unsigned int u16) {
    unsigned int v = u16 << 16;
    float f;
    __builtin_memcpy(&f, &v, 4);
    return f;
}

// ---- async global->LDS (16B per lane; LDS dest is wave-uniform base) ------
__device__ __forceinline__ void gload16(const void* g, void* l) {
    __builtin_amdgcn_global_load_lds(
        (const __attribute__((address_space(1))) void*)g,
        (__attribute__((address_space(3))) void*)l, 16, 0, 0);
}

// ---- 8-elem loader for either dtype (runtime flag) ------------------------
__device__ __forceinline__ void load8f_rt(const void* p, int isf, float* f) {
    if (isf) {
        const float* q = (const float*)p;
        float4 a = *(const float4*)q;
        float4 b = *(const float4*)(q + 4);
        f[0] = a.x; f[1] = a.y; f[2] = a.z; f[3] = a.w;
        f[4] = b.x; f[5] = b.y; f[6] = b.z; f[7] = b.w;
    } else {
        uint4 u = *(const uint4*)p;
        f[0] = bits2f(u.x & 0xffffu); f[1] = bits2f(u.x >> 16);
        f[2] = bits2f(u.y & 0xffffu); f[3] = bits2f(u.y >> 16);
        f[4] = bits2f(u.z & 0xffffu); f[5] = bits2f(u.z >> 16);
        f[6] = bits2f(u.w & 0xffffu); f[7] = bits2f(u.w >> 16);
    }
}
__device__ __forceinline__ float loadf_rt(const void* p, int isf, size_t i) {
    return isf ? ((const float*)p)[i] : bits2f(((const ushort*)p)[i]);
}

// ---- one-time conversion (single kernel, runtime dtype, inline detect) ----
// Each block redundantly probes x[0..2048) (4KB, L2-resident) to decide the
// dtype; block 0 publishes dflag[0] for the later LN kernels. Removes the
// serial 1-block detect kernel + its dependency bubble.
// wall layout (ushort): wq@0 wk@589824 wv@1179648 wo@1769472 w1@2359296 w2@4718592
// vall layout (float):  bq@0 bk@768 bv@1536 bo@2304 b1@3072 b2@6144
//                       g1@6912 be1@7680 g2@8448 be2@9216   (total 9984)
__global__ __launch_bounds__(256) void conv_all_k(
    int* __restrict__ dflag,
    const void* __restrict__ x,
    const void* __restrict__ wq, const void* __restrict__ wk,
    const void* __restrict__ wv, const void* __restrict__ wo,
    const void* __restrict__ w1, const void* __restrict__ w2,
    const void* __restrict__ bq, const void* __restrict__ bk,
    const void* __restrict__ bv, const void* __restrict__ bo,
    const void* __restrict__ b1, const void* __restrict__ b2,
    const void* __restrict__ g1, const void* __restrict__ be1,
    const void* __restrict__ g2, const void* __restrict__ be2,
    ushort* __restrict__ xb, ushort* __restrict__ wall,
    float* __restrict__ vall)
{
    __shared__ int cnt;
    if (threadIdx.x == 0) cnt = 0;
    __syncthreads();
    {
        const ushort* xs = (const ushort*)x;
        int local = 0;
        for (int i = threadIdx.x; i < 2048; i += 256) {
            float v = bits2f((unsigned int)xs[i]);
            if (!(fabsf(v) < 1e4f)) local++;  // also true for NaN/Inf
        }
        atomicAdd(&cnt, local);
    }
    __syncthreads();
    const int isf = (cnt >= 8) ? 1 : 0;
    if (blockIdx.x == 0 && threadIdx.x == 0) dflag[0] = isf;

    const int esz = isf ? 4 : 2;
    const int gt = blockIdx.x * 256 + threadIdx.x;
    const int stride = gridDim.x * 256;

    // x -> bf16
    for (int v = gt; v < 393216; v += stride) {  // 3,145,728 / 8
        float f[8];
        load8f_rt((const char*)x + (size_t)v * 8 * esz, isf, f);
        unsigned int wd[4];
        #pragma unroll
        for (int i = 0; i < 4; ++i)
            wd[i] = (unsigned int)f2bu(f[2 * i]) | ((unsigned int)f2bu(f[2 * i + 1]) << 16);
        *(uint4*)(xb + (size_t)v * 8) = make_uint4(wd[0], wd[1], wd[2], wd[3]);
    }
    // weights -> bf16
    for (int v = gt; v < 884736; v += stride) {  // 7,077,888 / 8
        const void* src; int loc;
        if (v < 73728)        { src = wq; loc = v; }
        else if (v < 147456)  { src = wk; loc = v - 73728; }
        else if (v < 221184)  { src = wv; loc = v - 147456; }
        else if (v < 294912)  { src = wo; loc = v - 221184; }
        else if (v < 589824)  { src = w1; loc = v - 294912; }
        else                  { src = w2; loc = v - 589824; }
        float f[8];
        load8f_rt((const char*)src + (size_t)loc * 8 * esz, isf, f);
        unsigned int wd[4];
        #pragma unroll
        for (int i = 0; i < 4; ++i)
            wd[i] = (unsigned int)f2bu(f[2 * i]) | ((unsigned int)f2bu(f[2 * i + 1]) << 16);
        *(uint4*)(wall + (size_t)v * 8) = make_uint4(wd[0], wd[1], wd[2], wd[3]);
    }
    // vectors -> f32
    for (int i = gt; i < 9984; i += stride) {
        const void* s; int l;
        if (i < 768)       { s = bq;  l = i; }
        else if (i < 1536) { s = bk;  l = i - 768; }
        else if (i < 2304) { s = bv;  l = i - 1536; }
        else if (i < 3072) { s = bo;  l = i - 2304; }
        else if (i < 6144) { s = b1;  l = i - 3072; }
        else if (i < 6912) { s = b2;  l = i - 6144; }
        else if (i < 7680) { s = g1;  l = i - 6912; }
        else if (i < 8448) { s = be1; l = i - 7680; }
        else if (i < 9216) { s = g2;  l = i - 8448; }
        else               { s = be2; l = i - 9216; }
        vall[i] = loadf_rt(s, isf, l);
    }
}

// ========== bf16 MFMA GEMM, BK=64, XOR-swizzled LDS, 2-phase dbuf ==========
// (round-5 verified inner structure; K-range [kstart, kstart+klen) for
// split-K; nullable bias.)
// Frag layouts (m89-verified): A-frag m=lane&15, k=quad*8+j;
// B-frag n=lane&15, k=quad*8+j; C/D col=lane&15, row=quad*4+reg.
template <int BM>
__device__ __forceinline__ void gemm_bf16_body(
    const ushort* __restrict__ A, const ushort* __restrict__ Bw,
    const float* __restrict__ bias, ushort* __restrict__ Cb,
    float* __restrict__ Cf, int N, int K, int kstart, int klen,
    int bm, int bn, int relu)
{
    __shared__ __align__(16) ushort As[2][BM][64];   // [buf][m][k], 128B rows
    __shared__ __align__(16) ushort Bs[2][128][64];  // [buf][n][k]
    const int tid = threadIdx.x;
    const int w = tid >> 6, lane = tid & 63;
    const int quad = lane >> 4, l15 = lane & 15;
    constexpr int FM = BM / 32;                    // frags per wave in M
    const int wr = (w >> 1) * (BM / 2), wc = (w & 1) * 64;

    constexpr int CA = (BM * 128) / 4096;          // 4KB rounds for A tile
    constexpr int CB = 4;                          // 128*128B/4KB
    size_t aoff[CA]; int albase[CA];
    #pragma unroll
    for (int c = 0; c < CA; ++c) {
        int byte = c * 4096 + tid * 16;
        int row = byte >> 7, colb = byte & 127;
        int csrc = colb ^ ((row & 7) << 4);        // inverse swizzle on SOURCE
        aoff[c] = (size_t)(bm + row) * K + (csrc >> 1);
        albase[c] = c * 4096 + w * 1024;           // wave-uniform LDS base
    }
    size_t boff[CB]; int blbase[CB];
    #pragma unroll
    for (int c = 0; c < CB; ++c) {
        int byte = c * 4096 + tid * 16;
        int row = byte >> 7, colb = byte & 127;
        int csrc = colb ^ ((row & 7) << 4);
        boff[c] = (size_t)(bn + row) * K + (csrc >> 1);
        blbase[c] = c * 4096 + w * 1024;
    }

    f32x4 acc[FM][4];
    #pragma unroll
    for (int i = 0; i < FM; ++i)
        #pragma unroll
        for (int j = 0; j < 4; ++j) acc[i][j] = (f32x4){0.f, 0.f, 0.f, 0.f};

    constexpr int ASZ = BM * 128;      // bytes per A buffer
    constexpr int BSZ = 128 * 128;     // bytes per B buffer

#define STAGE(buf, k0)                                                        \
    {                                                                         \
        char* ab = (char*)As + (buf) * ASZ;                                   \
        char* bb = (char*)Bs + (buf) * BSZ;                                   \
        _Pragma("unroll")                                                     \
        for (int c = 0; c < CA; ++c)                                          \
            gload16(A + aoff[c] + (k0), ab + albase[c]);                      \
        _Pragma("unroll")                                                     \
        for (int c = 0; c < CB; ++c)                                          \
            gload16(Bw + boff[c] + (k0), bb + blbase[c]);                     \
    }

    const int NT = klen >> 6;
    STAGE(0, kstart);
    int cur = 0;
    for (int t = 0; t < NT; ++t) {
        __syncthreads();                 // buf[cur] visible (vmcnt drained)
        if (t + 1 < NT) STAGE(cur ^ 1, kstart + (t + 1) * 64);

        const ushort (*Asb)[64] = As[cur];
        const ushort (*Bsb)[64] = Bs[cur];
        short8 af[FM][2], bfr[4][2];
        #pragma unroll
        for (int i = 0; i < FM; ++i) {
            int r = wr + i * 16 + l15;
            int sw = (r & 7) << 3;                 // XOR key in ushort units
            af[i][0] = *(const short8*)&Asb[r][(quad * 8) ^ sw];
            af[i][1] = *(const short8*)&Asb[r][(32 + quad * 8) ^ sw];
        }
        #pragma unroll
        for (int j = 0; j < 4; ++j) {
            int r = wc + j * 16 + l15;
            int sw = (r & 7) << 3;
            bfr[j][0] = *(const short8*)&Bsb[r][(quad * 8) ^ sw];
            bfr[j][1] = *(const short8*)&Bsb[r][(32 + quad * 8) ^ sw];
        }
        #pragma unroll
        for (int h = 0; h < 2; ++h)
            #pragma unroll
            for (int i = 0; i < FM; ++i)
                #pragma unroll
                for (int j = 0; j < 4; ++j)
                    acc[i][j] = __builtin_amdgcn_mfma_f32_16x16x32_bf16(
                        af[i][h], bfr[j][h], acc[i][j], 0, 0, 0);
        cur ^= 1;
    }
#undef STAGE

    #pragma unroll
    for (int j = 0; j < 4; ++j) {
        int col = bn + wc + j * 16 + l15;
        float bv = bias ? bias[col] : 0.f;
        #pragma unroll
        for (int i = 0; i < FM; ++i) {
            int row0 = bm + wr + i * 16 + quad * 4;
            #pragma unroll
            for (int r = 0; r < 4; ++r) {
                float vv = acc[i][j][r] + bv;
                if (relu) vv = fmaxf(vv, 0.f);
                size_t idx = (size_t)(row0 + r) * N + col;
                if (Cb) Cb[idx] = f2bu(vv);
                if (Cf) Cf[idx] = vv;
            }
        }
    }
}

// XCD-aware bijective block swizzle (grids here are all %8 == 0)
__device__ __forceinline__ int xcd_swz(int bid, int nwg) {
    int cpx = nwg >> 3;
    return (bid & 7) * cpx + (bid >> 3);
}

template <int BM>
__global__ __launch_bounds__(256) void gemm_b(
    const ushort* __restrict__ A, const ushort* __restrict__ Bw,
    const float* __restrict__ bias, ushort* __restrict__ Cb,
    float* __restrict__ Cf, int N, int K, int relu)
{
    int nwg = gridDim.x * gridDim.y;
    int bid = xcd_swz(blockIdx.y * gridDim.x + blockIdx.x, nwg);
    int bx = bid % gridDim.x, by = bid / gridDim.x;
    gemm_bf16_body<BM>(A, Bw, bias, Cb, Cf, N, K, 0, K, by * BM, bx * 128, relu);
}

// split-K x2 GEMM: grid (nx, ny, 2); part z writes f32 partial Cf + z*nxd;
// bias added in part 0 only. LN kernels downstream sum the two partials.
template <int BM>
__global__ __launch_bounds__(256) void gemm_ksplit(
    const ushort* __restrict__ A, const ushort* __restrict__ Bw,
    const float* __restrict__ bias, float* __restrict__ Cf, int N, int K)
{
    const int part = blockIdx.z;
    int nwg = gridDim.x * gridDim.y;
    int bid = xcd_swz(blockIdx.y * gridDim.x + blockIdx.x, nwg);
    int bx = bid % gridDim.x, by = bid / gridDim.x;
    const int kh = K >> 1;
    gemm_bf16_body<BM>(A, Bw, part ? nullptr : bias, nullptr,
                       Cf + (size_t)part * 3145728, N, K,
                       part * kh, kh, by * BM, bx * 128, 0);
}

// Fused QKV: BM=64 (48KB LDS -> 3 blocks/CU); grid (18, 64)
__global__ __launch_bounds__(256) void gemm_qkv_b(
    const ushort* __restrict__ x, const ushort* __restrict__ wall,
    const float* __restrict__ vall,
    ushort* __restrict__ qb, ushort* __restrict__ kb, ushort* __restrict__ vb)
{
    int bid = xcd_swz(blockIdx.y * 18 + blockIdx.x, 1152);
    int bx = bid % 18, by = bid / 18;
    const int mat = bx / 6;
    const int bn = (bx % 6) * 128;
    const ushort* W = wall + (size_t)mat * 589824;
    const float* Bi = vall + mat * 768;
    ushort* O = (mat == 0) ? qb : (mat == 1) ? kb : vb;
    gemm_bf16_body<64>(x, W, Bi, O, nullptr, 768, 768, 0, 768, by * 64, bn, 0);
}

// ============== bf16 MFMA flash attention, split-K x NP, 8-wave ============
// (round-9/10 verified core + T1 XCD-chunked swizzle; NP templated.)
// Round-16 change: partials written as BF16 (halves partial write traffic
// and combine read traffic); (m,l) stay f32.
template <int NP>
__global__ __launch_bounds__(512) void attn_mfma_b(
    const ushort* __restrict__ q, const ushort* __restrict__ k,
    const ushort* __restrict__ v, const int* __restrict__ mask,
    ushort* __restrict__ opart, float* __restrict__ mlbuf)
{
    const int S = 2048, D = 768;
    constexpr int SPK = 2048 / NP;   // keys per part
    constexpr int NT = SPK / 64;     // tiles per part
    const size_t NXD = 3145728;
    const float SC2 = 0.125f * 1.44269504088896f;   // score scale in log2 units
    __shared__ __align__(16) ushort Ks[64][72];     // [key][dim]
    __shared__ __align__(16) ushort Vt[64][72];     // [dim][key]
    __shared__ __align__(16) ushort Ps[8][16][72];  // per-wave P, XOR-swizzled
    __shared__ float mkAll[SPK];                    // additive mask bias (part)

    const int tid = threadIdx.x;
    const int w = tid >> 6, lane = tid & 63;
    const int quad = lane >> 4, l15 = lane & 15;

    // T1: XCD-chunked swizzle (bijective, NP*384 % 8 == 0)
    const int bx = xcd_swz(blockIdx.x, NP * 384);
    const int part = bx / 384;
    const int rest = bx - part * 384;
    const int q0 = (rest & 15) * 128;
    const int h = (rest >> 4) % 12;
    const int b = rest / 192;
    const int kbase = part * SPK;

    // hoist the part's mask flags once
    #pragma unroll
    for (int i = 0; i < SPK / 512; ++i) {
        int idx = tid + i * 512;
        mkAll[idx] = mask[b * S + kbase + idx] ? -30000.f : 0.f;
    }

    const size_t qrow = (size_t)(b * S + q0 + w * 16 + l15) * D + h * 64;
    const short8 aQ0 = *(const short8*)&q[qrow + quad * 8];
    const short8 aQ1 = *(const short8*)&q[qrow + 32 + quad * 8];

    short8 ones;
    #pragma unroll
    for (int j = 0; j < 8; ++j) ones[j] = (short)0x3F80;  // bf16 1.0

    f32x4 o[4], lacc;
    #pragma unroll
    for (int i = 0; i < 4; ++i) o[i] = (f32x4){0.f, 0.f, 0.f, 0.f};
    lacc = (f32x4){0.f, 0.f, 0.f, 0.f};
    float m_run = -3.0e38f;

    const int sr = tid >> 3;          // K staging: key row 0..63
    const int sc0 = (tid & 7) * 8;    // K staging: dim base (ushorts)

    const ushort* kp = k + (size_t)(b * S + kbase + sr) * D + h * 64 + sc0;
    const ushort* vp = v + (size_t)(b * S + kbase + lane) * D + h * 64 + w * 8;
    uint4 ka = *(const uint4*)kp;
    uint4 va = *(const uint4*)vp;

    for (int kt = 0; kt < NT; ++kt) {
        __syncthreads();  // previous tile's consumers done
        *(uint4*)&Ks[sr][sc0] = ka;
        {   // conflict-free transpose: wave w owns dims [w*8, w*8+8), lane=key
            alignas(16) ushort tmp[8];
            *(uint4*)tmp = va;
            #pragma unroll
            for (int i = 0; i < 8; ++i) Vt[w * 8 + i][lane] = tmp[i];
        }
        __syncthreads();  // tile visible

        // ---- prefetch next tile (flies under compute) ----
        if (kt + 1 < NT) {
            kp += 64 * D;
            vp += 64 * D;
            ka = *(const uint4*)kp;
            va = *(const uint4*)vp;
        }

        // ---- QK^T (log2 domain, additive mask) ----
        const float* mk = &mkAll[kt * 64];
        float scv[4][4];
        float vm = -3.0e38f;
        __builtin_amdgcn_s_setprio(1);
        #pragma unroll
        for (int s = 0; s < 4; ++s) {
            short8 bk0 = *(const short8*)&Ks[s * 16 + l15][quad * 8];
            short8 bk1 = *(const short8*)&Ks[s * 16 + l15][32 + quad * 8];
            f32x4 c = (f32x4){0.f, 0.f, 0.f, 0.f};
            c = __builtin_amdgcn_mfma_f32_16x16x32_bf16(aQ0, bk0, c, 0, 0, 0);
            c = __builtin_amdgcn_mfma_f32_16x16x32_bf16(aQ1, bk1, c, 0, 0, 0);
            float mb = mk[s * 16 + l15];
            #pragma unroll
            for (int r = 0; r < 4; ++r) {
                float val = __builtin_fmaf(c[r], SC2, mb);
                scv[s][r] = val;
                vm = fmaxf(vm, val);
            }
        }
        __builtin_amdgcn_s_setprio(0);
        // group max over keys (16 l15-lanes); shared by this quad's 4 q-rows
        vm = fmaxf(vm, __shfl_xor(vm, 1, 16));
        vm = fmaxf(vm, __shfl_xor(vm, 2, 16));
        vm = fmaxf(vm, __shfl_xor(vm, 4, 16));
        vm = fmaxf(vm, __shfl_xor(vm, 8, 16));

        // defer-max: rescale only when tile max grows past threshold
        if (__any(vm > m_run + 11.0f)) {
            float mn = fmaxf(m_run, vm);
            float alpha = exp2f(m_run - mn);
            #pragma unroll
            for (int s = 0; s < 4; ++s) o[s] *= alpha;
            lacc *= alpha;
            m_run = mn;
        }

        // P = exp2(scv - m_run) -> bf16, XOR-swizzled per-wave store
        #pragma unroll
        for (int r = 0; r < 4; ++r)
            #pragma unroll
            for (int s = 0; s < 4; ++s)
                Ps[w][quad * 4 + r][(s * 16 + l15) ^ (quad << 4)] =
                    f2bu(exp2f(scv[s][r] - m_run));
        asm volatile("s_waitcnt lgkmcnt(0)" ::: "memory");

        // ---- PV + l (ones column) ----
        {
            const int pswz = (l15 >> 2) << 4;
            short8 aP0 = *(const short8*)&Ps[w][l15][(quad * 8) ^ pswz];
            short8 aP1 = *(const short8*)&Ps[w][l15][(32 + quad * 8) ^ pswz];
            __builtin_amdgcn_s_setprio(1);
            lacc = __builtin_amdgcn_mfma_f32_16x16x32_bf16(aP0, ones, lacc, 0, 0, 0);
            lacc = __builtin_amdgcn_mfma_f32_16x16x32_bf16(aP1, ones, lacc, 0, 0, 0);
            #pragma unroll
            for (int s = 0; s < 4; ++s) {
                short8 bv0 = *(const short8*)&Vt[s * 16 + l15][quad * 8];
                short8 bv1 = *(const short8*)&Vt[s * 16 + l15][32 + quad * 8];
                o[s] = __builtin_amdgcn_mfma_f32_16x16x32_bf16(aP0, bv0, o[s], 0, 0, 0);
                o[s] = __builtin_amdgcn_mfma_f32_16x16x32_bf16(aP1, bv1, o[s], 0, 0, 0);
            }
            __builtin_amdgcn_s_setprio(0);
        }
    }

    // ---- epilogue: unnormalized BF16 partial + f32 (m,l) in log2 domain ---
    const size_t obase = (size_t)part * NXD +
                         (size_t)(b * S + q0 + w * 16) * D + h * 64;
    #pragma unroll
    for (int r = 0; r < 4; ++r)
        #pragma unroll
        for (int s = 0; s < 4; ++s)
            opart[obase + (size_t)(quad * 4 + r) * D + s * 16 + l15] =
                f2bu(o[s][r]);
    if (l15 == 0) {
        #pragma unroll
        for (int r = 0; r < 4; ++r) {
            int row = b * S + q0 + w * 16 + quad * 4 + r;
            size_t mi = (((size_t)part * 4096 + row) * 12 + h) * 2;
            mlbuf[mi] = m_run;
            mlbuf[mi + 1] = lacc[r];
        }
    }
}

// ---- combine NP bf16 split-K partials -> bf16 ctx (log2-domain m,l) -------
template <int NP>
__global__ __launch_bounds__(256) void attn_combine(
    const ushort* __restrict__ opart, const float* __restrict__ mlbuf,
    ushort* __restrict__ ctx)
{
    const size_t NXD = 3145728;
    const int row = blockIdx.x;
    const int tid = threadIdx.x;
    #pragma unroll
    for (int i = 0; i < 3; ++i) {
        int d = tid + i * 256;
        int h = d >> 6;
        float mv[NP], lv[NP];
        float m = -3.0e38f;
        #pragma unroll
        for (int p = 0; p < NP; ++p) {
            size_t mi = (((size_t)p * 4096 + row) * 12 + h) * 2;
            mv[p] = mlbuf[mi];
            lv[p] = mlbuf[mi + 1];
            m = fmaxf(m, mv[p]);
        }
        size_t idx = (size_t)row * 768 + d;
        float den = 0.f, num = 0.f;
        #pragma unroll
        for (int p = 0; p < NP; ++p) {
            float e = exp2f(mv[p] - m);
            den += lv[p] * e;
            num += bits2f((unsigned int)opart[(size_t)p * NXD + idx]) * e;
        }
        ctx[idx] = f2bu(num / den);
    }
}

// ---- LN1: out = LN(x + (r0+r1)); runtime x dtype; bf16 + f32 out ----------
__global__ __launch_bounds__(256) void ln1_kernel(
    const int* __restrict__ dflag,
    const void* __restrict__ xa, const float* __restrict__ r0,
    const float* __restrict__ r1,
    const float* __restrict__ gamma, const float* __restrict__ beta,
    ushort* __restrict__ outb, float* __restrict__ outf)
{
    const int isf = dflag[0];
    const int row = blockIdx.x;
    const int tid = threadIdx.x;
    __shared__ float red[4];
    const size_t base = (size_t)row * 768;

    float x[3];
    #pragma unroll
    for (int i = 0; i < 3; ++i) {
        int d = tid + i * 256;
        x[i] = loadf_rt(xa, isf, base + d) + r0[base + d] + r1[base + d];
    }

    float s = x[0] + x[1] + x[2];
    #pragma unroll
    for (int off = 32; off > 0; off >>= 1) s += __shfl_down(s, off, 64);
    if ((tid & 63) == 0) red[tid >> 6] = s;
    __syncthreads();
    float mean = (red[0] + red[1] + red[2] + red[3]) * (1.f / 768.f);
    __syncthreads();

    float vsum = 0.f;
    #pragma unroll
    for (int i = 0; i < 3; ++i) {
        float dd = x[i] - mean;
        vsum += dd * dd;
    }
    #pragma unroll
    for (int off = 32; off > 0; off >>= 1) vsum += __shfl_down(vsum, off, 64);
    if ((tid & 63) == 0) red[tid >> 6] = vsum;
    __syncthreads();
    float var = (red[0] + red[1] + red[2] + red[3]) * (1.f / 767.f);
    float inv = 1.f / (sqrtf(var) + 1e-6f);

    #pragma unroll
    for (int i = 0; i < 3; ++i) {
        int d = tid + i * 256;
        float y = gamma[d] * (x[i] - mean) * inv + beta[d];
        outb[base + d] = f2bu(y);
        outf[base + d] = y;
    }
}

// ---- LN2 (final): out = LN(ln1f + (f0+f1)); runtime out dtype -------------
__global__ __launch_bounds__(256) void ln2_kernel(
    const int* __restrict__ dflag,
    const float* __restrict__ a, const float* __restrict__ f0,
    const float* __restrict__ f1,
    const float* __restrict__ gamma, const float* __restrict__ beta,
    void* __restrict__ out)
{
    const int isf = dflag[0];
    const int row = blockIdx.x;
    const int tid = threadIdx.x;
    __shared__ float red[4];
    const size_t base = (size_t)row * 768;

    float x[3];
    #pragma unroll
    for (int i = 0; i < 3; ++i) {
        int d = tid + i * 256;
        x[i] = a[base + d] + f0[base + d] + f1[base + d];
    }

    float s = x[0] + x[1] + x[2];
    #pragma unroll
    for (int off = 32; off > 0; off >>= 1) s += __shfl_down(s, off, 64);
    if ((tid & 63) == 0) red[tid >> 6] = s;
    __syncthreads();
    float mean = (red[0] + red[1] + red[2] + red[3]) * (1.f / 768.f);
    __syncthreads();

    float vsum = 0.f;
    #pragma unroll
    for (int i = 0; i < 3; ++i) {
        float dd = x[i] - mean;
        vsum += dd * dd;
    }
    #pragma unroll
    for (int off = 32; off > 0; off >>= 1) vsum += __shfl_down(vsum, off, 64);
    if ((tid & 63) == 0) red[tid >> 6] = vsum;
    __syncthreads();
    float var = (red[0] + red[1] + red[2] + red[3]) * (1.f / 767.f);
    float inv = 1.f / (sqrtf(var) + 1e-6f);

    #pragma unroll
    for (int i = 0; i < 3; ++i) {
        int d = tid + i * 256;
        float y = gamma[d] * (x[i] - mean) * inv + beta[d];
        if (isf) ((float*)out)[base + d] = y;
        else     ((ushort*)out)[base + d] = f2bu(y);
    }
}

extern "C" void kernel_launch(void* const* d_in, const int* in_sizes, int n_in,
                              void* d_out, int out_size, void* d_ws, size_t ws_size,
                              hipStream_t stream) {
    const size_t nxd = 3145728;   // 4096*768
    char* base = (char*)d_ws;
    int* dflag = (int*)base;

    // workspace layout:
    //  A: xb (bf16 x) -> later ln1b          6.3MB
    //  B: wall 14.2MB, vall 40KB
    //  C: qb|kb|vb|ctx (4*nxd bf16) -> ff1b  25.2MB
    //  D,E: f32 nxd each (attn bf16 partials [NP<=4 fit in D+E] ->
    //       oproj f32 partials -> ff2 f32 partials)
    //  G: f32 nxd (attn mlbuf [NP2]; later ln1f)
    //  M: mlbuf for NP4 (1.6MB)
    char* p = base + 256;
    ushort* xb   = (ushort*)p; p += nxd * 2;            // A
    ushort* wall = (ushort*)p; p += 7077888ull * 2;     // B
    float*  vall = (float*)p;  p += 40960;
    ushort* qb   = (ushort*)p;                          // C
    ushort* kb   = qb + nxd;
    ushort* vb   = kb + nxd;
    ushort* ctx  = vb + nxd;
    ushort* ff1b = qb;
    p += 4 * nxd * 2;
    float* dbuf = (float*)p; p += nxd * 4;              // D
    float* ebuf = (float*)p; p += nxd * 4;              // E
    float* gbuf = (float*)p; p += nxd * 4;              // G (mlbuf2 / ln1f)
    float* mbuf = (float*)p; p += 4 * 4096 * 12 * 2 * 4;  // M (NP4 mlbuf)
    size_t need4 = (size_t)((char*)(mbuf + 393216) - base);

    ushort* opartb = (ushort*)dbuf;  // NP bf16 partials, contiguous (<= D+E)
    ushort* ln1b = xb;               // xb dead after QKV
    float* ln1f = gbuf;              // written after attn partials consumed

    const int* mask = (const int*)d_in[1];
    dim3 blk(256);

    conv_all_k<<<dim3(1024), blk, 0, stream>>>(dflag,
        d_in[0], d_in[2], d_in[4], d_in[6], d_in[8], d_in[10], d_in[12],
        d_in[3], d_in[5], d_in[7], d_in[9], d_in[11], d_in[13],
        d_in[14], d_in[15], d_in[16], d_in[17], xb, wall, vall);

    // QKV: M=4096, N=768 x3, K=768; BM=64 -> 1152 blocks (3 blocks/CU)
    gemm_qkv_b<<<dim3(18, 64), blk, 0, stream>>>(xb, wall, vall, qb, kb, vb);

    // attention: split-K x4 if workspace allows, else x2
    if (ws_size >= need4) {
        attn_mfma_b<4><<<dim3(1536), dim3(512), 0, stream>>>(
            qb, kb, vb, mask, opartb, mbuf);
        attn_combine<4><<<dim3(4096), blk, 0, stream>>>(opartb, mbuf, ctx);
    } else {
        attn_mfma_b<2><<<dim3(768), dim3(512), 0, stream>>>(
            qb, kb, vb, mask, opartb, gbuf);
        attn_combine<2><<<dim3(4096), blk, 0, stream>>>(opartb, gbuf, ctx);
    }

    // O-proj: M=4096, N=768, K=768, split-K x2 -> f32 partials D,E
    gemm_ksplit<64><<<dim3(6, 64, 2), blk, 0, stream>>>(
        ctx, wall + 1769472, vall + 2304, dbuf, 768, 768);

    ln1_kernel<<<dim3(4096), blk, 0, stream>>>(dflag,
        d_in[0], dbuf, ebuf, vall + 6912, vall + 7680, ln1b, ln1f);

    // FF1: M=4096, N=3072, K=768, relu -> bf16; BM=64 -> 1536 blocks (3/CU)
    gemm_b<64><<<dim3(24, 64), blk, 0, stream>>>(
        ln1b, wall + 2359296, vall + 3072, ff1b, nullptr, 3072, 768, 1);

    // FF2: M=4096, N=768, K=3072, split-K x2 -> f32 partials D,E
    gemm_ksplit<64><<<dim3(6, 64, 2), blk, 0, stream>>>(
        ff1b, wall + 4718592, vall + 6144, dbuf, 768, 3072);

    ln2_kernel<<<dim3(4096), blk, 0, stream>>>(dflag,
        ln1f, dbuf, ebuf, vall + 8448, vall + 9216, d_out);
}